// Round 1
// baseline (2402.506 us; speedup 1.0000x reference)
//
#include <hip/hip_runtime.h>
#include <hip/hip_bf16.h>
#include <cstddef>

#define NA 200000   // atoms
#define EA 800000   // atom-graph edges
#define NF 20000    // fragments
#define EF 60000    // fragment-graph edges
// D = 128, hidden = 256

// ---------- degree / dinv ----------
__global__ __launch_bounds__(256) void k_init_deg(float* __restrict__ deg) {
  int i = blockIdx.x * 256 + threadIdx.x;
  if (i < NA) deg[i] = 1.0f;  // self-loop contributes 1
}

__global__ __launch_bounds__(256) void k_accum_deg(const int* __restrict__ ei,
                                                   float* __restrict__ deg) {
  int e = blockIdx.x * 256 + threadIdx.x;
  if (e < EA) unsafeAtomicAdd(&deg[ei[e]], 1.0f);  // deg over src = edge_index[0]
}

__global__ __launch_bounds__(256) void k_dinv(float* __restrict__ deg) {
  int i = blockIdx.x * 256 + threadIdx.x;
  if (i < NA) deg[i] = rsqrtf(deg[i]);  // deg >= 1 always (self loops)
}

// ---------- x = x_atoms @ W_atom + b_atom ; x_new = x * dinv^2 (self-loop) ----------
// 256 thr: c = tid&127 (output col), rg = tid>>7; 16 rows/block, 8 rows/thread.
__global__ __launch_bounds__(256) void k_gemm_atom(
    const float* __restrict__ xa, const float* __restrict__ W,
    const float* __restrict__ b, const float* __restrict__ dinv,
    float* __restrict__ x, float* __restrict__ xnew) {
  const int c = threadIdx.x & 127;
  const int rg = threadIdx.x >> 7;
  const int row0 = blockIdx.x * 16 + rg * 8;
  float acc[8] = {0.f, 0.f, 0.f, 0.f, 0.f, 0.f, 0.f, 0.f};
  const float* xr = xa + (size_t)row0 * 128;
  for (int k = 0; k < 128; ++k) {
    float w = W[k * 128 + c];
#pragma unroll
    for (int r = 0; r < 8; ++r) acc[r] += xr[r * 128 + k] * w;
  }
  const float bc = b[c];
#pragma unroll
  for (int r = 0; r < 8; ++r) {
    const int row = row0 + r;
    const float v = acc[r] + bc;
    x[(size_t)row * 128 + c] = v;
    const float di = dinv[row];
    xnew[(size_t)row * 128 + c] = v * di * di;  // self-loop norm = dinv[i]^2
  }
}

// ---------- edge propagation: x_new[t] += x[s] * dinv[s]*dinv[t] ----------
// 32 threads/edge, float4 each (128 floats per row).
__global__ __launch_bounds__(256) void k_edge_prop(
    const int* __restrict__ ei, const float* __restrict__ x,
    const float* __restrict__ dinv, float* __restrict__ xnew) {
  const long long g = (long long)blockIdx.x * 256 + threadIdx.x;
  const int e = (int)(g >> 5);
  if (e >= EA) return;
  const int c = ((int)g & 31) << 2;
  const int s = ei[e];        // edge_index[0][e] = src
  const int t = ei[EA + e];   // edge_index[1][e] = tgt
  const float w = dinv[s] * dinv[t];
  const float4 v = *reinterpret_cast<const float4*>(x + (size_t)s * 128 + c);
  float* o = xnew + (size_t)t * 128 + c;
  unsafeAtomicAdd(o + 0, v.x * w);
  unsafeAtomicAdd(o + 1, v.y * w);
  unsafeAtomicAdd(o + 2, v.z * w);
  unsafeAtomicAdd(o + 3, v.w * w);
}

// ---------- fragment pooling: frag_feat[a2f[i]] += x_new[i] ----------
__global__ __launch_bounds__(256) void k_frag_pool(
    const float* __restrict__ xnew, const int* __restrict__ a2f,
    float* __restrict__ ff) {
  const long long g = (long long)blockIdx.x * 256 + threadIdx.x;
  const int i = (int)(g >> 5);
  if (i >= NA) return;
  const int c = ((int)g & 31) << 2;
  const int f = a2f[i];
  const float4 v = *reinterpret_cast<const float4*>(xnew + (size_t)i * 128 + c);
  float* o = ff + (size_t)f * 128 + c;
  unsafeAtomicAdd(o + 0, v.x);
  unsafeAtomicAdd(o + 1, v.y);
  unsafeAtomicAdd(o + 2, v.z);
  unsafeAtomicAdd(o + 3, v.w);
}

// ---------- frag edges: frag_sum[ft] += frag_feat[fs] ----------
__global__ __launch_bounds__(256) void k_frag_edge(
    const int* __restrict__ fi, const float* __restrict__ ff,
    float* __restrict__ fsum) {
  const long long g = (long long)blockIdx.x * 256 + threadIdx.x;
  const int e = (int)(g >> 5);
  if (e >= EF) return;
  const int c = ((int)g & 31) << 2;
  const int s = fi[e];        // frag_index[0][e]
  const int t = fi[EF + e];   // frag_index[1][e]
  const float4 v = *reinterpret_cast<const float4*>(ff + (size_t)s * 128 + c);
  float* o = fsum + (size_t)t * 128 + c;
  unsafeAtomicAdd(o + 0, v.x);
  unsafeAtomicAdd(o + 1, v.y);
  unsafeAtomicAdd(o + 2, v.z);
  unsafeAtomicAdd(o + 3, v.w);
}

// ---------- h = relu(frag_sum @ W_f1 + b_f1), [NF,128]@[128,256] ----------
__global__ __launch_bounds__(256) void k_gemm_f1(
    const float* __restrict__ A, const float* __restrict__ W,
    const float* __restrict__ b, float* __restrict__ h) {
  const int c = threadIdx.x;            // 0..255
  const int row0 = blockIdx.x * 8;
  float acc[8] = {0.f, 0.f, 0.f, 0.f, 0.f, 0.f, 0.f, 0.f};
  const float* Ar = A + (size_t)row0 * 128;
  for (int k = 0; k < 128; ++k) {
    float w = W[k * 256 + c];
#pragma unroll
    for (int r = 0; r < 8; ++r) acc[r] += Ar[r * 128 + k] * w;
  }
  const float bc = b[c];
#pragma unroll
  for (int r = 0; r < 8; ++r)
    h[(size_t)(row0 + r) * 256 + c] = fmaxf(acc[r] + bc, 0.0f);
}

// ---------- frag_out = h @ W_f2 + b_f2, [NF,256]@[256,128] ----------
__global__ __launch_bounds__(256) void k_gemm_f2(
    const float* __restrict__ Hm, const float* __restrict__ W,
    const float* __restrict__ b, float* __restrict__ out) {
  const int c = threadIdx.x & 127;
  const int rg = threadIdx.x >> 7;
  const int row0 = blockIdx.x * 16 + rg * 8;
  float acc[8] = {0.f, 0.f, 0.f, 0.f, 0.f, 0.f, 0.f, 0.f};
  const float* Hr = Hm + (size_t)row0 * 256;
  for (int k = 0; k < 256; ++k) {
    float w = W[k * 128 + c];
#pragma unroll
    for (int r = 0; r < 8; ++r) acc[r] += Hr[r * 256 + k] * w;
  }
  const float bc = b[c];
#pragma unroll
  for (int r = 0; r < 8; ++r)
    out[(size_t)(row0 + r) * 128 + c] = acc[r] + bc;
}

extern "C" void kernel_launch(void* const* d_in, const int* in_sizes, int n_in,
                              void* d_out, int out_size, void* d_ws, size_t ws_size,
                              hipStream_t stream) {
  // Inputs (setup_inputs order). Bond-graph GAT inputs are dead code:
  // the reference discards new_bond/edge embedding; outputs depend only on
  // the atom GCN + fragment pipeline.
  const float* x_atoms   = (const float*)d_in[0];
  const int*   edge_index = (const int*)d_in[1];
  const int*   frag_index = (const int*)d_in[3];
  const int*   a2f        = (const int*)d_in[5];
  const float* W_atom    = (const float*)d_in[9];
  const float* b_atom    = (const float*)d_in[10];
  const float* W_f1      = (const float*)d_in[16];
  const float* b_f1      = (const float*)d_in[17];
  const float* W_f2      = (const float*)d_in[18];
  const float* b_f2      = (const float*)d_in[19];

  char* ws = (char*)d_ws;
  float* dinv = (float*)(ws);                                   // 0.8 MB
  float* x    = (float*)(ws + (1 << 20));                       // 102.4 MB
  float* ff   = (float*)(ws + (1 << 20) + 102400000);           // 10.24 MB
  float* fsum = (float*)(ws + (1 << 20) + 112640000);           // 10.24 MB
  float* h    = (float*)(ws + (1 << 20) + 122880000);           // 20.48 MB

  float* xnew = (float*)d_out;                    // [NA,128]
  float* fout = (float*)d_out + (size_t)NA * 128; // [NF,128]

  // zero the two scatter targets each call (harness does not re-poison)
  hipMemsetAsync(ws + (1 << 20) + 102400000, 0, 20480000, stream);

  k_init_deg <<<(NA + 255) / 256, 256, 0, stream>>>(dinv);
  k_accum_deg<<<(EA + 255) / 256, 256, 0, stream>>>(edge_index, dinv);
  k_dinv     <<<(NA + 255) / 256, 256, 0, stream>>>(dinv);

  k_gemm_atom<<<NA / 16, 256, 0, stream>>>(x_atoms, W_atom, b_atom, dinv, x, xnew);

  k_edge_prop<<<(int)(((long long)EA * 32 + 255) / 256), 256, 0, stream>>>(
      edge_index, x, dinv, xnew);

  k_frag_pool<<<(int)(((long long)NA * 32 + 255) / 256), 256, 0, stream>>>(
      xnew, a2f, ff);
  k_frag_edge<<<(int)(((long long)EF * 32 + 255) / 256), 256, 0, stream>>>(
      frag_index, ff, fsum);

  k_gemm_f1<<<NF / 8, 256, 0, stream>>>(fsum, W_f1, b_f1, h);
  k_gemm_f2<<<NF / 16, 256, 0, stream>>>(h, W_f2, b_f2, fout);
}

// Round 2
// 796.923 us; speedup vs baseline: 3.0147x; 3.0147x over previous
//
#include <hip/hip_runtime.h>
#include <hip/hip_bf16.h>
#include <cstddef>

#define NA 200000   // atoms
#define EA 800000   // atom-graph edges
#define NF 20000    // fragments
#define EF 60000    // fragment-graph edges
// D = 128, hidden = 256

// ================= degree / dinv (tiny; float atomics are fine here) ========
__global__ __launch_bounds__(256) void k_init_deg(float* __restrict__ deg) {
  int i = blockIdx.x * 256 + threadIdx.x;
  if (i < NA) deg[i] = 1.0f;  // self loop
}
__global__ __launch_bounds__(256) void k_accum_deg(const int* __restrict__ ei,
                                                   float* __restrict__ deg) {
  int e = blockIdx.x * 256 + threadIdx.x;
  if (e < EA) unsafeAtomicAdd(&deg[ei[e]], 1.0f);  // deg over src = edge_index[0]
}
__global__ __launch_bounds__(256) void k_dinv(float* __restrict__ deg) {
  int i = blockIdx.x * 256 + threadIdx.x;
  if (i < NA) deg[i] = rsqrtf(deg[i]);
}

// ================= CSR build: histogram -> scan -> fill =====================
__global__ __launch_bounds__(256) void k_hist_e(const int* __restrict__ ei,
                                                int* __restrict__ cnt) {
  int e = blockIdx.x * 256 + threadIdx.x;
  if (e < EA) atomicAdd(&cnt[ei[EA + e]], 1);  // by tgt
}
__global__ __launch_bounds__(256) void k_hist_a(const int* __restrict__ a2f,
                                                int* __restrict__ cnt) {
  int i = blockIdx.x * 256 + threadIdx.x;
  if (i < NA) atomicAdd(&cnt[a2f[i]], 1);
}
__global__ __launch_bounds__(256) void k_hist_f(const int* __restrict__ fi,
                                                int* __restrict__ cnt) {
  int e = blockIdx.x * 256 + threadIdx.x;
  if (e < EF) atomicAdd(&cnt[fi[EF + e]], 1);  // by ft
}

// exclusive scan, 1024 elems/block (256 thr x 4)
__global__ __launch_bounds__(256) void k_scan1(const int* __restrict__ cnt,
                                               int* __restrict__ rp,
                                               int* __restrict__ bsum, int n) {
  __shared__ int sh[256];
  const int base = blockIdx.x * 1024;
  const int tid = threadIdx.x;
  int v[4], s = 0;
#pragma unroll
  for (int j = 0; j < 4; ++j) {
    int idx = base + tid * 4 + j;
    v[j] = (idx < n) ? cnt[idx] : 0;
    s += v[j];
  }
  sh[tid] = s;
  __syncthreads();
  for (int off = 1; off < 256; off <<= 1) {
    int t = (tid >= off) ? sh[tid - off] : 0;
    __syncthreads();
    sh[tid] += t;
    __syncthreads();
  }
  int excl = (tid > 0) ? sh[tid - 1] : 0;
#pragma unroll
  for (int j = 0; j < 4; ++j) {
    int idx = base + tid * 4 + j;
    if (idx < n) rp[idx] = excl;
    excl += v[j];
  }
  if (tid == 255) bsum[blockIdx.x] = sh[255];
}
__global__ __launch_bounds__(1024) void k_scan2(int* __restrict__ bsum, int nb) {
  __shared__ int sh[1024];
  const int tid = threadIdx.x;
  sh[tid] = (tid < nb) ? bsum[tid] : 0;
  __syncthreads();
  for (int off = 1; off < 1024; off <<= 1) {
    int t = (tid >= off) ? sh[tid - off] : 0;
    __syncthreads();
    sh[tid] += t;
    __syncthreads();
  }
  if (tid < nb) bsum[tid] = (tid > 0) ? sh[tid - 1] : 0;  // exclusive
}
__global__ __launch_bounds__(256) void k_scan3(int* __restrict__ rp,
                                               const int* __restrict__ bsum,
                                               int n) {
  int i = blockIdx.x * 256 + threadIdx.x;
  if (i < n) rp[i] += bsum[i >> 10];
}

__global__ __launch_bounds__(256) void k_fill_e(const int* __restrict__ ei,
                                                const int* __restrict__ rp,
                                                int* __restrict__ cur,
                                                int* __restrict__ lst) {
  int e = blockIdx.x * 256 + threadIdx.x;
  if (e >= EA) return;
  int t = ei[EA + e];
  int p = atomicAdd(&cur[t], 1);
  lst[rp[t] + p] = ei[e];  // store src
}
__global__ __launch_bounds__(256) void k_fill_a(const int* __restrict__ a2f,
                                                const int* __restrict__ rp,
                                                int* __restrict__ cur,
                                                int* __restrict__ lst) {
  int i = blockIdx.x * 256 + threadIdx.x;
  if (i >= NA) return;
  int f = a2f[i];
  int p = atomicAdd(&cur[f], 1);
  lst[rp[f] + p] = i;  // store atom id
}
__global__ __launch_bounds__(256) void k_fill_f(const int* __restrict__ fi,
                                                const int* __restrict__ rp,
                                                int* __restrict__ cur,
                                                int* __restrict__ lst) {
  int e = blockIdx.x * 256 + threadIdx.x;
  if (e >= EF) return;
  int t = fi[EF + e];
  int p = atomicAdd(&cur[t], 1);
  lst[rp[t] + p] = fi[e];  // store fs
}

// ======== y = (x_atoms @ W_atom + b_atom) * dinv[row] =======================
__global__ __launch_bounds__(256) void k_gemm_y(
    const float* __restrict__ xa, const float* __restrict__ W,
    const float* __restrict__ b, const float* __restrict__ dinv,
    float* __restrict__ y) {
  const int c = threadIdx.x & 127;
  const int rg = threadIdx.x >> 7;
  const int row0 = blockIdx.x * 16 + rg * 8;
  float acc[8] = {0.f, 0.f, 0.f, 0.f, 0.f, 0.f, 0.f, 0.f};
  const float* xr = xa + (size_t)row0 * 128;
  for (int k = 0; k < 128; ++k) {
    float w = W[k * 128 + c];
#pragma unroll
    for (int r = 0; r < 8; ++r) acc[r] += xr[r * 128 + k] * w;
  }
  const float bc = b[c];
#pragma unroll
  for (int r = 0; r < 8; ++r) {
    const int row = row0 + r;
    y[(size_t)row * 128 + c] = (acc[r] + bc) * dinv[row];
  }
}

// ======== x_new[t] = dinv[t] * (y[t] + sum_{s->t} y[s])  (CSR gather) =======
__global__ __launch_bounds__(256) void k_gather_x(
    const int* __restrict__ rp, const int* __restrict__ cnt,
    const int* __restrict__ lst, const float* __restrict__ y,
    const float* __restrict__ dinv, float* __restrict__ xnew) {
  const int row = blockIdx.x * 8 + (threadIdx.x >> 5);
  const int c = (threadIdx.x & 31) << 2;
  float4 acc = *reinterpret_cast<const float4*>(y + (size_t)row * 128 + c);
  const int start = rp[row];
  const int deg = cnt[row];
  for (int j = 0; j < deg; ++j) {
    const int s = lst[start + j];
    const float4 v = *reinterpret_cast<const float4*>(y + (size_t)s * 128 + c);
    acc.x += v.x; acc.y += v.y; acc.z += v.z; acc.w += v.w;
  }
  const float dt = dinv[row];
  acc.x *= dt; acc.y *= dt; acc.z *= dt; acc.w *= dt;
  *reinterpret_cast<float4*>(xnew + (size_t)row * 128 + c) = acc;
}

// ======== ff[f] = sum_{atoms i in f} xnew[i]  (CSR gather) ==================
__global__ __launch_bounds__(256) void k_gather_ff(
    const int* __restrict__ rp, const int* __restrict__ cnt,
    const int* __restrict__ lst, const float* __restrict__ xnew,
    float* __restrict__ ff) {
  const int f = blockIdx.x * 8 + (threadIdx.x >> 5);
  const int c = (threadIdx.x & 31) << 2;
  float4 acc = {0.f, 0.f, 0.f, 0.f};
  const int start = rp[f];
  const int deg = cnt[f];
  for (int j = 0; j < deg; ++j) {
    const int i = lst[start + j];
    const float4 v = *reinterpret_cast<const float4*>(xnew + (size_t)i * 128 + c);
    acc.x += v.x; acc.y += v.y; acc.z += v.z; acc.w += v.w;
  }
  *reinterpret_cast<float4*>(ff + (size_t)f * 128 + c) = acc;
}

// ======== fsum[t] = sum_{fs->t} ff[fs]  (CSR gather, no self) ===============
__global__ __launch_bounds__(256) void k_gather_fs(
    const int* __restrict__ rp, const int* __restrict__ cnt,
    const int* __restrict__ lst, const float* __restrict__ ff,
    float* __restrict__ fsum) {
  const int f = blockIdx.x * 8 + (threadIdx.x >> 5);
  const int c = (threadIdx.x & 31) << 2;
  float4 acc = {0.f, 0.f, 0.f, 0.f};
  const int start = rp[f];
  const int deg = cnt[f];
  for (int j = 0; j < deg; ++j) {
    const int s = lst[start + j];
    const float4 v = *reinterpret_cast<const float4*>(ff + (size_t)s * 128 + c);
    acc.x += v.x; acc.y += v.y; acc.z += v.z; acc.w += v.w;
  }
  *reinterpret_cast<float4*>(fsum + (size_t)f * 128 + c) = acc;
}

// ======== frag_out = relu(fsum@W1+b1)@W2+b2, fused via 8KB LDS ==============
__global__ __launch_bounds__(256) void k_mlp(
    const float* __restrict__ A, const float* __restrict__ W1,
    const float* __restrict__ b1, const float* __restrict__ W2,
    const float* __restrict__ b2, float* __restrict__ out) {
  __shared__ float hs[8][256];
  const int row0 = blockIdx.x * 8;
  const int c = threadIdx.x;  // hidden col 0..255
  float acc[8] = {0.f, 0.f, 0.f, 0.f, 0.f, 0.f, 0.f, 0.f};
  const float* Ar = A + (size_t)row0 * 128;
  for (int k = 0; k < 128; ++k) {
    float w = W1[k * 256 + c];
#pragma unroll
    for (int r = 0; r < 8; ++r) acc[r] += Ar[r * 128 + k] * w;
  }
  const float bc = b1[c];
#pragma unroll
  for (int r = 0; r < 8; ++r) hs[r][c] = fmaxf(acc[r] + bc, 0.f);
  __syncthreads();
  const int c2 = threadIdx.x & 127;
  const int rh = threadIdx.x >> 7;  // 0/1 -> rows rh*4..rh*4+3
  float acc2[4] = {0.f, 0.f, 0.f, 0.f};
  for (int k = 0; k < 256; ++k) {
    float w = W2[k * 128 + c2];
#pragma unroll
    for (int r = 0; r < 4; ++r) acc2[r] += hs[rh * 4 + r][k] * w;
  }
  const float bc2 = b2[c2];
#pragma unroll
  for (int r = 0; r < 4; ++r)
    out[(size_t)(row0 + rh * 4 + r) * 128 + c2] = acc2[r] + bc2;
}

extern "C" void kernel_launch(void* const* d_in, const int* in_sizes, int n_in,
                              void* d_out, int out_size, void* d_ws, size_t ws_size,
                              hipStream_t stream) {
  // Bond-graph GAT inputs are dead code w.r.t. the returned outputs.
  const float* x_atoms    = (const float*)d_in[0];
  const int*   edge_index = (const int*)d_in[1];
  const int*   frag_index = (const int*)d_in[3];
  const int*   a2f        = (const int*)d_in[5];
  const float* W_atom     = (const float*)d_in[9];
  const float* b_atom     = (const float*)d_in[10];
  const float* W_f1       = (const float*)d_in[16];
  const float* b_f1       = (const float*)d_in[17];
  const float* W_f2       = (const float*)d_in[18];
  const float* b_f2       = (const float*)d_in[19];

  char* ws = (char*)d_ws;
  size_t off = 0;
  auto alloc = [&](size_t bytes) {
    void* p = ws + off;
    off += (bytes + 255) & ~(size_t)255;
    return p;
  };
  // --- zeroed-each-call int pool (histogram counters + fill cursors) ---
  int* cnt_e = (int*)alloc(NA * 4);
  int* cur_e = (int*)alloc(NA * 4);
  int* cnt_a = (int*)alloc(NF * 4);
  int* cur_a = (int*)alloc(NF * 4);
  int* cnt_f = (int*)alloc(NF * 4);
  int* cur_f = (int*)alloc(NF * 4);
  const size_t zero_bytes = off;  // contiguous from ws start
  // --- CSR arrays (fully rewritten each call) ---
  int* rp_e   = (int*)alloc(NA * 4);
  int* rp_a   = (int*)alloc(NF * 4);
  int* rp_f   = (int*)alloc(NF * 4);
  int* bsum   = (int*)alloc(1024 * 4);
  int* lst_e  = (int*)alloc((size_t)EA * 4);
  int* lst_a  = (int*)alloc(NA * 4);
  int* lst_f  = (int*)alloc(EF * 4);
  // --- float buffers ---
  float* dinv = (float*)alloc(NA * 4);
  float* y    = (float*)alloc((size_t)NA * 128 * 4);
  float* ff   = (float*)alloc((size_t)NF * 128 * 4);
  float* fsum = (float*)alloc((size_t)NF * 128 * 4);

  float* xnew = (float*)d_out;                     // [NA,128]
  float* fout = (float*)d_out + (size_t)NA * 128;  // [NF,128]

  hipMemsetAsync(ws, 0, zero_bytes, stream);

  // degree / dinv (over src = edge_index[0], + self loop)
  k_init_deg <<<(NA + 255) / 256, 256, 0, stream>>>(dinv);
  k_accum_deg<<<(EA + 255) / 256, 256, 0, stream>>>(edge_index, dinv);
  k_dinv     <<<(NA + 255) / 256, 256, 0, stream>>>(dinv);

  // CSR by tgt for atom edges
  k_hist_e<<<(EA + 255) / 256, 256, 0, stream>>>(edge_index, cnt_e);
  {
    int nb = (NA + 1023) / 1024;
    k_scan1<<<nb, 256, 0, stream>>>(cnt_e, rp_e, bsum, NA);
    k_scan2<<<1, 1024, 0, stream>>>(bsum, nb);
    k_scan3<<<(NA + 255) / 256, 256, 0, stream>>>(rp_e, bsum, NA);
  }
  k_fill_e<<<(EA + 255) / 256, 256, 0, stream>>>(edge_index, rp_e, cur_e, lst_e);

  // CSR atoms->frags
  k_hist_a<<<(NA + 255) / 256, 256, 0, stream>>>(a2f, cnt_a);
  {
    int nb = (NF + 1023) / 1024;
    k_scan1<<<nb, 256, 0, stream>>>(cnt_a, rp_a, bsum, NF);
    k_scan2<<<1, 1024, 0, stream>>>(bsum, nb);
    k_scan3<<<(NF + 255) / 256, 256, 0, stream>>>(rp_a, bsum, NF);
  }
  k_fill_a<<<(NA + 255) / 256, 256, 0, stream>>>(a2f, rp_a, cur_a, lst_a);

  // CSR frag edges by ft
  k_hist_f<<<(EF + 255) / 256, 256, 0, stream>>>(frag_index, cnt_f);
  {
    int nb = (NF + 1023) / 1024;
    k_scan1<<<nb, 256, 0, stream>>>(cnt_f, rp_f, bsum, NF);
    k_scan2<<<1, 1024, 0, stream>>>(bsum, nb);
    k_scan3<<<(NF + 255) / 256, 256, 0, stream>>>(rp_f, bsum, NF);
  }
  k_fill_f<<<(EF + 255) / 256, 256, 0, stream>>>(frag_index, rp_f, cur_f, lst_f);

  // main pipeline
  k_gemm_y  <<<NA / 16, 256, 0, stream>>>(x_atoms, W_atom, b_atom, dinv, y);
  k_gather_x<<<NA / 8, 256, 0, stream>>>(rp_e, cnt_e, lst_e, y, dinv, xnew);
  k_gather_ff<<<NF / 8, 256, 0, stream>>>(rp_a, cnt_a, lst_a, xnew, ff);
  k_gather_fs<<<NF / 8, 256, 0, stream>>>(rp_f, cnt_f, lst_f, ff, fsum);
  k_mlp     <<<NF / 8, 256, 0, stream>>>(fsum, W_f1, b_f1, W_f2, b_f2, fout);
}

// Round 3
// 547.549 us; speedup vs baseline: 4.3877x; 1.4554x over previous
//
#include <hip/hip_runtime.h>
#include <hip/hip_bf16.h>
#include <cstddef>

#define NA 200000   // atoms
#define EA 800000   // atom-graph edges
#define NF 20000    // fragments
#define EF 60000    // fragment-graph edges
// D = 128, hidden = 256

// ================= degree / dinv ============================================
__global__ __launch_bounds__(256) void k_init_deg(float* __restrict__ deg) {
  int i = blockIdx.x * 256 + threadIdx.x;
  if (i < NA) deg[i] = 1.0f;  // self loop
}
__global__ __launch_bounds__(256) void k_accum_deg(const int* __restrict__ ei,
                                                   float* __restrict__ deg) {
  int e = blockIdx.x * 256 + threadIdx.x;
  if (e < EA) unsafeAtomicAdd(&deg[ei[e]], 1.0f);  // deg over src = edge_index[0]
}
__global__ __launch_bounds__(256) void k_dinv(float* __restrict__ deg) {
  int i = blockIdx.x * 256 + threadIdx.x;
  if (i < NA) deg[i] = rsqrtf(deg[i]);
}

// ================= CSR build: histogram -> scan -> fill =====================
__global__ __launch_bounds__(256) void k_hist_e(const int* __restrict__ ei,
                                                int* __restrict__ cnt) {
  int e = blockIdx.x * 256 + threadIdx.x;
  if (e < EA) atomicAdd(&cnt[ei[EA + e]], 1);  // by tgt
}
__global__ __launch_bounds__(256) void k_hist_a(const int* __restrict__ a2f,
                                                int* __restrict__ cnt) {
  int i = blockIdx.x * 256 + threadIdx.x;
  if (i < NA) atomicAdd(&cnt[a2f[i]], 1);
}
__global__ __launch_bounds__(256) void k_hist_f(const int* __restrict__ fi,
                                                int* __restrict__ cnt) {
  int e = blockIdx.x * 256 + threadIdx.x;
  if (e < EF) atomicAdd(&cnt[fi[EF + e]], 1);  // by ft
}

// exclusive scan, 1024 elems/block (256 thr x 4)
__global__ __launch_bounds__(256) void k_scan1(const int* __restrict__ cnt,
                                               int* __restrict__ rp,
                                               int* __restrict__ bsum, int n) {
  __shared__ int sh[256];
  const int base = blockIdx.x * 1024;
  const int tid = threadIdx.x;
  int v[4], s = 0;
#pragma unroll
  for (int j = 0; j < 4; ++j) {
    int idx = base + tid * 4 + j;
    v[j] = (idx < n) ? cnt[idx] : 0;
    s += v[j];
  }
  sh[tid] = s;
  __syncthreads();
  for (int off = 1; off < 256; off <<= 1) {
    int t = (tid >= off) ? sh[tid - off] : 0;
    __syncthreads();
    sh[tid] += t;
    __syncthreads();
  }
  int excl = (tid > 0) ? sh[tid - 1] : 0;
#pragma unroll
  for (int j = 0; j < 4; ++j) {
    int idx = base + tid * 4 + j;
    if (idx < n) rp[idx] = excl;
    excl += v[j];
  }
  if (tid == 255) bsum[blockIdx.x] = sh[255];
}
__global__ __launch_bounds__(1024) void k_scan2(int* __restrict__ bsum, int nb) {
  __shared__ int sh[1024];
  const int tid = threadIdx.x;
  sh[tid] = (tid < nb) ? bsum[tid] : 0;
  __syncthreads();
  for (int off = 1; off < 1024; off <<= 1) {
    int t = (tid >= off) ? sh[tid - off] : 0;
    __syncthreads();
    sh[tid] += t;
    __syncthreads();
  }
  if (tid < nb) bsum[tid] = (tid > 0) ? sh[tid - 1] : 0;  // exclusive
}
__global__ __launch_bounds__(256) void k_scan3(int* __restrict__ rp,
                                               const int* __restrict__ bsum,
                                               int n) {
  int i = blockIdx.x * 256 + threadIdx.x;
  if (i < n) rp[i] += bsum[i >> 10];
}

__global__ __launch_bounds__(256) void k_fill_e(const int* __restrict__ ei,
                                                const int* __restrict__ rp,
                                                int* __restrict__ cur,
                                                int* __restrict__ lst) {
  int e = blockIdx.x * 256 + threadIdx.x;
  if (e >= EA) return;
  int t = ei[EA + e];
  int p = atomicAdd(&cur[t], 1);
  lst[rp[t] + p] = ei[e];  // store src
}
__global__ __launch_bounds__(256) void k_fill_a(const int* __restrict__ a2f,
                                                const int* __restrict__ rp,
                                                int* __restrict__ cur,
                                                int* __restrict__ lst) {
  int i = blockIdx.x * 256 + threadIdx.x;
  if (i >= NA) return;
  int f = a2f[i];
  int p = atomicAdd(&cur[f], 1);
  lst[rp[f] + p] = i;  // store atom id
}
__global__ __launch_bounds__(256) void k_fill_f(const int* __restrict__ fi,
                                                const int* __restrict__ rp,
                                                int* __restrict__ cur,
                                                int* __restrict__ lst) {
  int e = blockIdx.x * 256 + threadIdx.x;
  if (e >= EF) return;
  int t = fi[EF + e];
  int p = atomicAdd(&cur[t], 1);
  lst[rp[t] + p] = fi[e];  // store fs
}

// ======== y = (x_atoms @ W_atom + b_atom) * dinv[row] =======================
// Register-tiled outer product: thread = 8 rows x 4 cols; k chunked by 4.
// Block = 64 rows x 128 cols (256 thr: tc=tid&31 -> cols, tr=tid>>5 -> rows).
__global__ __launch_bounds__(256) void k_gemm_y(
    const float* __restrict__ xa, const float* __restrict__ W,
    const float* __restrict__ b, const float* __restrict__ dinv,
    float* __restrict__ y) {
  const int tc = threadIdx.x & 31;
  const int tr = threadIdx.x >> 5;
  const int row0 = blockIdx.x * 64 + tr * 8;
  const int c0 = tc * 4;
  float acc[8][4] = {};
  const float* Ar = xa + (size_t)row0 * 128;
  for (int k0 = 0; k0 < 128; k0 += 4) {
    float4 w0 = *reinterpret_cast<const float4*>(&W[(k0 + 0) * 128 + c0]);
    float4 w1 = *reinterpret_cast<const float4*>(&W[(k0 + 1) * 128 + c0]);
    float4 w2 = *reinterpret_cast<const float4*>(&W[(k0 + 2) * 128 + c0]);
    float4 w3 = *reinterpret_cast<const float4*>(&W[(k0 + 3) * 128 + c0]);
#pragma unroll
    for (int r = 0; r < 8; ++r) {
      float4 a = *reinterpret_cast<const float4*>(&Ar[r * 128 + k0]);
      acc[r][0] += a.x * w0.x + a.y * w1.x + a.z * w2.x + a.w * w3.x;
      acc[r][1] += a.x * w0.y + a.y * w1.y + a.z * w2.y + a.w * w3.y;
      acc[r][2] += a.x * w0.z + a.y * w1.z + a.z * w2.z + a.w * w3.z;
      acc[r][3] += a.x * w0.w + a.y * w1.w + a.z * w2.w + a.w * w3.w;
    }
  }
  const float4 bc = *reinterpret_cast<const float4*>(&b[c0]);
#pragma unroll
  for (int r = 0; r < 8; ++r) {
    const int row = row0 + r;
    const float di = dinv[row];
    float4 o;
    o.x = (acc[r][0] + bc.x) * di;
    o.y = (acc[r][1] + bc.y) * di;
    o.z = (acc[r][2] + bc.z) * di;
    o.w = (acc[r][3] + bc.w) * di;
    *reinterpret_cast<float4*>(&y[(size_t)row * 128 + c0]) = o;
  }
}

// ======== x_new[t] = dinv[t] * (y[t] + sum_{s->t} y[s])  (CSR gather) =======
__global__ __launch_bounds__(256) void k_gather_x(
    const int* __restrict__ rp, const int* __restrict__ cnt,
    const int* __restrict__ lst, const float* __restrict__ y,
    const float* __restrict__ dinv, float* __restrict__ xnew) {
  const int row = blockIdx.x * 8 + (threadIdx.x >> 5);
  const int c = (threadIdx.x & 31) << 2;
  float4 acc = *reinterpret_cast<const float4*>(y + (size_t)row * 128 + c);
  const int start = rp[row];
  const int deg = cnt[row];
  for (int j = 0; j < deg; ++j) {
    const int s = lst[start + j];
    const float4 v = *reinterpret_cast<const float4*>(y + (size_t)s * 128 + c);
    acc.x += v.x; acc.y += v.y; acc.z += v.z; acc.w += v.w;
  }
  const float dt = dinv[row];
  acc.x *= dt; acc.y *= dt; acc.z *= dt; acc.w *= dt;
  *reinterpret_cast<float4*>(xnew + (size_t)row * 128 + c) = acc;
}

// ======== ff[f] = sum_{atoms i in f} xnew[i]  (CSR gather) ==================
__global__ __launch_bounds__(256) void k_gather_ff(
    const int* __restrict__ rp, const int* __restrict__ cnt,
    const int* __restrict__ lst, const float* __restrict__ xnew,
    float* __restrict__ ff) {
  const int f = blockIdx.x * 8 + (threadIdx.x >> 5);
  const int c = (threadIdx.x & 31) << 2;
  float4 acc = {0.f, 0.f, 0.f, 0.f};
  const int start = rp[f];
  const int deg = cnt[f];
  for (int j = 0; j < deg; ++j) {
    const int i = lst[start + j];
    const float4 v = *reinterpret_cast<const float4*>(xnew + (size_t)i * 128 + c);
    acc.x += v.x; acc.y += v.y; acc.z += v.z; acc.w += v.w;
  }
  *reinterpret_cast<float4*>(ff + (size_t)f * 128 + c) = acc;
}

// ======== fsum[t] = sum_{fs->t} ff[fs]  (CSR gather, no self) ===============
__global__ __launch_bounds__(256) void k_gather_fs(
    const int* __restrict__ rp, const int* __restrict__ cnt,
    const int* __restrict__ lst, const float* __restrict__ ff,
    float* __restrict__ fsum) {
  const int f = blockIdx.x * 8 + (threadIdx.x >> 5);
  const int c = (threadIdx.x & 31) << 2;
  float4 acc = {0.f, 0.f, 0.f, 0.f};
  const int start = rp[f];
  const int deg = cnt[f];
  for (int j = 0; j < deg; ++j) {
    const int s = lst[start + j];
    const float4 v = *reinterpret_cast<const float4*>(ff + (size_t)s * 128 + c);
    acc.x += v.x; acc.y += v.y; acc.z += v.z; acc.w += v.w;
  }
  *reinterpret_cast<float4*>(fsum + (size_t)f * 128 + c) = acc;
}

// ======== frag_out = relu(fsum@W1+b1)@W2+b2, fused, register-tiled ==========
// Block = 32 rows. GEMM1: 256 thr as tc=tid&63 (cols c0=tc*4 of 256),
// tr=tid>>6 (0..3) -> rows tr*8..+7. hs in LDS [32][256]. GEMM2: tc=tid&31
// (cols of 128), tr=tid>>5 (0..7) -> rows tr*4..+3, A from LDS.
__global__ __launch_bounds__(256) void k_mlp(
    const float* __restrict__ A, const float* __restrict__ W1,
    const float* __restrict__ b1, const float* __restrict__ W2,
    const float* __restrict__ b2, float* __restrict__ out) {
  __shared__ float hs[32][256];
  const int row0 = blockIdx.x * 32;
  {
    const int tc = threadIdx.x & 63;
    const int tr = threadIdx.x >> 6;
    const int c0 = tc * 4;
    const float* Ar = A + (size_t)(row0 + tr * 8) * 128;
    float acc[8][4] = {};
    for (int k0 = 0; k0 < 128; k0 += 4) {
      float4 w0 = *reinterpret_cast<const float4*>(&W1[(k0 + 0) * 256 + c0]);
      float4 w1 = *reinterpret_cast<const float4*>(&W1[(k0 + 1) * 256 + c0]);
      float4 w2 = *reinterpret_cast<const float4*>(&W1[(k0 + 2) * 256 + c0]);
      float4 w3 = *reinterpret_cast<const float4*>(&W1[(k0 + 3) * 256 + c0]);
#pragma unroll
      for (int r = 0; r < 8; ++r) {
        float4 a = *reinterpret_cast<const float4*>(&Ar[r * 128 + k0]);
        acc[r][0] += a.x * w0.x + a.y * w1.x + a.z * w2.x + a.w * w3.x;
        acc[r][1] += a.x * w0.y + a.y * w1.y + a.z * w2.y + a.w * w3.y;
        acc[r][2] += a.x * w0.z + a.y * w1.z + a.z * w2.z + a.w * w3.z;
        acc[r][3] += a.x * w0.w + a.y * w1.w + a.z * w2.w + a.w * w3.w;
      }
    }
    const float4 bc = *reinterpret_cast<const float4*>(&b1[c0]);
#pragma unroll
    for (int r = 0; r < 8; ++r) {
      float4 h;
      h.x = fmaxf(acc[r][0] + bc.x, 0.f);
      h.y = fmaxf(acc[r][1] + bc.y, 0.f);
      h.z = fmaxf(acc[r][2] + bc.z, 0.f);
      h.w = fmaxf(acc[r][3] + bc.w, 0.f);
      *reinterpret_cast<float4*>(&hs[tr * 8 + r][c0]) = h;
    }
  }
  __syncthreads();
  {
    const int tc = threadIdx.x & 31;
    const int tr = threadIdx.x >> 5;
    const int c0 = tc * 4;
    float acc[4][4] = {};
    for (int k0 = 0; k0 < 256; k0 += 4) {
      float4 w0 = *reinterpret_cast<const float4*>(&W2[(k0 + 0) * 128 + c0]);
      float4 w1 = *reinterpret_cast<const float4*>(&W2[(k0 + 1) * 128 + c0]);
      float4 w2 = *reinterpret_cast<const float4*>(&W2[(k0 + 2) * 128 + c0]);
      float4 w3 = *reinterpret_cast<const float4*>(&W2[(k0 + 3) * 128 + c0]);
#pragma unroll
      for (int r = 0; r < 4; ++r) {
        float4 a = *reinterpret_cast<const float4*>(&hs[tr * 4 + r][k0]);
        acc[r][0] += a.x * w0.x + a.y * w1.x + a.z * w2.x + a.w * w3.x;
        acc[r][1] += a.x * w0.y + a.y * w1.y + a.z * w2.y + a.w * w3.y;
        acc[r][2] += a.x * w0.z + a.y * w1.z + a.z * w2.z + a.w * w3.z;
        acc[r][3] += a.x * w0.w + a.y * w1.w + a.z * w2.w + a.w * w3.w;
      }
    }
    const float4 bc = *reinterpret_cast<const float4*>(&b2[c0]);
#pragma unroll
    for (int r = 0; r < 4; ++r) {
      float4 o;
      o.x = acc[r][0] + bc.x;
      o.y = acc[r][1] + bc.y;
      o.z = acc[r][2] + bc.z;
      o.w = acc[r][3] + bc.w;
      *reinterpret_cast<float4*>(&out[(size_t)(row0 + tr * 4 + r) * 128 + c0]) = o;
    }
  }
}

extern "C" void kernel_launch(void* const* d_in, const int* in_sizes, int n_in,
                              void* d_out, int out_size, void* d_ws, size_t ws_size,
                              hipStream_t stream) {
  // Bond-graph GAT inputs are dead code w.r.t. the returned outputs.
  const float* x_atoms    = (const float*)d_in[0];
  const int*   edge_index = (const int*)d_in[1];
  const int*   frag_index = (const int*)d_in[3];
  const int*   a2f        = (const int*)d_in[5];
  const float* W_atom     = (const float*)d_in[9];
  const float* b_atom     = (const float*)d_in[10];
  const float* W_f1       = (const float*)d_in[16];
  const float* b_f1       = (const float*)d_in[17];
  const float* W_f2       = (const float*)d_in[18];
  const float* b_f2       = (const float*)d_in[19];

  char* ws = (char*)d_ws;
  size_t off = 0;
  auto alloc = [&](size_t bytes) {
    void* p = ws + off;
    off += (bytes + 255) & ~(size_t)255;
    return p;
  };
  // --- zeroed-each-call int pool (histogram counters + fill cursors) ---
  int* cnt_e = (int*)alloc(NA * 4);
  int* cur_e = (int*)alloc(NA * 4);
  int* cnt_a = (int*)alloc(NF * 4);
  int* cur_a = (int*)alloc(NF * 4);
  int* cnt_f = (int*)alloc(NF * 4);
  int* cur_f = (int*)alloc(NF * 4);
  const size_t zero_bytes = off;  // contiguous from ws start
  // --- CSR arrays (fully rewritten each call) ---
  int* rp_e   = (int*)alloc(NA * 4);
  int* rp_a   = (int*)alloc(NF * 4);
  int* rp_f   = (int*)alloc(NF * 4);
  int* bsum   = (int*)alloc(1024 * 4);
  int* lst_e  = (int*)alloc((size_t)EA * 4);
  int* lst_a  = (int*)alloc(NA * 4);
  int* lst_f  = (int*)alloc(EF * 4);
  // --- float buffers ---
  float* dinv = (float*)alloc(NA * 4);
  float* y    = (float*)alloc((size_t)NA * 128 * 4);
  float* ff   = (float*)alloc((size_t)NF * 128 * 4);
  float* fsum = (float*)alloc((size_t)NF * 128 * 4);

  float* xnew = (float*)d_out;                     // [NA,128]
  float* fout = (float*)d_out + (size_t)NA * 128;  // [NF,128]

  hipMemsetAsync(ws, 0, zero_bytes, stream);

  // degree / dinv (over src = edge_index[0], + self loop)
  k_init_deg <<<(NA + 255) / 256, 256, 0, stream>>>(dinv);
  k_accum_deg<<<(EA + 255) / 256, 256, 0, stream>>>(edge_index, dinv);
  k_dinv     <<<(NA + 255) / 256, 256, 0, stream>>>(dinv);

  // CSR by tgt for atom edges
  k_hist_e<<<(EA + 255) / 256, 256, 0, stream>>>(edge_index, cnt_e);
  {
    int nb = (NA + 1023) / 1024;
    k_scan1<<<nb, 256, 0, stream>>>(cnt_e, rp_e, bsum, NA);
    k_scan2<<<1, 1024, 0, stream>>>(bsum, nb);
    k_scan3<<<(NA + 255) / 256, 256, 0, stream>>>(rp_e, bsum, NA);
  }
  k_fill_e<<<(EA + 255) / 256, 256, 0, stream>>>(edge_index, rp_e, cur_e, lst_e);

  // CSR atoms->frags
  k_hist_a<<<(NA + 255) / 256, 256, 0, stream>>>(a2f, cnt_a);
  {
    int nb = (NF + 1023) / 1024;
    k_scan1<<<nb, 256, 0, stream>>>(cnt_a, rp_a, bsum, NF);
    k_scan2<<<1, 1024, 0, stream>>>(bsum, nb);
    k_scan3<<<(NF + 255) / 256, 256, 0, stream>>>(rp_a, bsum, NF);
  }
  k_fill_a<<<(NA + 255) / 256, 256, 0, stream>>>(a2f, rp_a, cur_a, lst_a);

  // CSR frag edges by ft
  k_hist_f<<<(EF + 255) / 256, 256, 0, stream>>>(frag_index, cnt_f);
  {
    int nb = (NF + 1023) / 1024;
    k_scan1<<<nb, 256, 0, stream>>>(cnt_f, rp_f, bsum, NF);
    k_scan2<<<1, 1024, 0, stream>>>(bsum, nb);
    k_scan3<<<(NF + 255) / 256, 256, 0, stream>>>(rp_f, bsum, NF);
  }
  k_fill_f<<<(EF + 255) / 256, 256, 0, stream>>>(frag_index, rp_f, cur_f, lst_f);

  // main pipeline
  k_gemm_y  <<<NA / 64, 256, 0, stream>>>(x_atoms, W_atom, b_atom, dinv, y);
  k_gather_x<<<NA / 8, 256, 0, stream>>>(rp_e, cnt_e, lst_e, y, dinv, xnew);
  k_gather_ff<<<NF / 8, 256, 0, stream>>>(rp_a, cnt_a, lst_a, xnew, ff);
  k_gather_fs<<<NF / 8, 256, 0, stream>>>(rp_f, cnt_f, lst_f, ff, fsum);
  k_mlp     <<<NF / 32, 256, 0, stream>>>(fsum, W_f1, b_f1, W_f2, b_f2, fout);
}

// Round 4
// 440.365 us; speedup vs baseline: 5.4557x; 1.2434x over previous
//
#include <hip/hip_runtime.h>
#include <hip/hip_bf16.h>
#include <cstddef>

#define NA 200000   // atoms
#define EA 800000   // atom-graph edges
#define NF 20000    // fragments
#define EF 60000    // fragment-graph edges
// D = 128, hidden = 256
#define NSEG (NA + 2 * NF)          // concatenated count array length (240000)
#define TOTW (EA + NA + EF)         // fused hist/fill work items (1060000)

// ================= fused histogram ==========================================
// cnt_src[i]: out-degree over edge_index[0] (for dinv)
// cnt_all:   [cnt_e by tgt (NA) | cnt_a by frag (NF) | cnt_f by ft (NF)]
__global__ __launch_bounds__(256) void k_hist_all(
    const int* __restrict__ ei, const int* __restrict__ a2f,
    const int* __restrict__ fi, int* __restrict__ cnt_src,
    int* __restrict__ cnt_all) {
  int idx = blockIdx.x * 256 + threadIdx.x;
  if (idx < EA) {
    atomicAdd(&cnt_src[ei[idx]], 1);
    atomicAdd(&cnt_all[ei[EA + idx]], 1);
  } else if (idx < EA + NA) {
    atomicAdd(&cnt_all[NA + a2f[idx - EA]], 1);
  } else if (idx < TOTW) {
    atomicAdd(&cnt_all[NA + NF + fi[EF + (idx - EA - NA)]], 1);
  }
}

// ================= exclusive scan over cnt_all (global; 3 kernels) ==========
__global__ __launch_bounds__(256) void k_scan1(const int* __restrict__ cnt,
                                               int* __restrict__ rp,
                                               int* __restrict__ bsum, int n) {
  __shared__ int sh[256];
  const int base = blockIdx.x * 1024;
  const int tid = threadIdx.x;
  int v[4], s = 0;
#pragma unroll
  for (int j = 0; j < 4; ++j) {
    int idx = base + tid * 4 + j;
    v[j] = (idx < n) ? cnt[idx] : 0;
    s += v[j];
  }
  sh[tid] = s;
  __syncthreads();
  for (int off = 1; off < 256; off <<= 1) {
    int t = (tid >= off) ? sh[tid - off] : 0;
    __syncthreads();
    sh[tid] += t;
    __syncthreads();
  }
  int excl = (tid > 0) ? sh[tid - 1] : 0;
#pragma unroll
  for (int j = 0; j < 4; ++j) {
    int idx = base + tid * 4 + j;
    if (idx < n) rp[idx] = excl;
    excl += v[j];
  }
  if (tid == 255) bsum[blockIdx.x] = sh[255];
}
__global__ __launch_bounds__(1024) void k_scan2(int* __restrict__ bsum, int nb) {
  __shared__ int sh[1024];
  const int tid = threadIdx.x;
  sh[tid] = (tid < nb) ? bsum[tid] : 0;
  __syncthreads();
  for (int off = 1; off < 1024; off <<= 1) {
    int t = (tid >= off) ? sh[tid - off] : 0;
    __syncthreads();
    sh[tid] += t;
    __syncthreads();
  }
  if (tid < nb) bsum[tid] = (tid > 0) ? sh[tid - 1] : 0;  // exclusive
}
// + fused dinv = rsqrt(1 + out-degree)
__global__ __launch_bounds__(256) void k_scan3(int* __restrict__ rp,
                                               const int* __restrict__ bsum,
                                               const int* __restrict__ cnt_src,
                                               float* __restrict__ dinv, int n) {
  int i = blockIdx.x * 256 + threadIdx.x;
  if (i < n) rp[i] += bsum[i >> 10];
  if (i < NA) dinv[i] = rsqrtf((float)(1 + cnt_src[i]));
}

// ================= fused CSR fill ===========================================
__global__ __launch_bounds__(256) void k_fill_all(
    const int* __restrict__ ei, const int* __restrict__ a2f,
    const int* __restrict__ fi, const int* __restrict__ rp,
    int* __restrict__ cur, int* __restrict__ lst) {
  int idx = blockIdx.x * 256 + threadIdx.x;
  if (idx < EA) {
    int t = ei[EA + idx];
    int p = atomicAdd(&cur[t], 1);
    lst[rp[t] + p] = ei[idx];            // src atom
  } else if (idx < EA + NA) {
    int i = idx - EA;
    int f = NA + a2f[i];
    int p = atomicAdd(&cur[f], 1);
    lst[rp[f] + p] = i;                  // atom id
  } else if (idx < TOTW) {
    int e = idx - EA - NA;
    int t = NA + NF + fi[EF + e];
    int p = atomicAdd(&cur[t], 1);
    lst[rp[t] + p] = fi[e];              // fs
  }
}

// ======== y = (x_atoms @ W_atom + b_atom) * dinv[row] =======================
// Block = 64 rows x 128 cols; A tile (32 KB) bulk-staged into LDS first
// (8 outstanding float4 loads/thread), compute reads LDS broadcast b128.
__global__ __launch_bounds__(256) void k_gemm_y(
    const float* __restrict__ xa, const float* __restrict__ W,
    const float* __restrict__ b, const float* __restrict__ dinv,
    float* __restrict__ y) {
  __shared__ float As[64 * 128];
  const int tid = threadIdx.x;
  const int brow = blockIdx.x * 64;
  {
    const float4* gA = reinterpret_cast<const float4*>(xa + (size_t)brow * 128);
    float4 st[8];
#pragma unroll
    for (int i = 0; i < 8; ++i) st[i] = gA[tid + i * 256];
#pragma unroll
    for (int i = 0; i < 8; ++i)
      reinterpret_cast<float4*>(As)[tid + i * 256] = st[i];
  }
  __syncthreads();
  const int tc = tid & 31;
  const int tr = tid >> 5;
  const int c0 = tc * 4;
  const float* Ar = As + (tr * 8) * 128;
  float acc[8][4] = {};
#pragma unroll 2
  for (int k0 = 0; k0 < 128; k0 += 4) {
    float4 w0 = *reinterpret_cast<const float4*>(&W[(k0 + 0) * 128 + c0]);
    float4 w1 = *reinterpret_cast<const float4*>(&W[(k0 + 1) * 128 + c0]);
    float4 w2 = *reinterpret_cast<const float4*>(&W[(k0 + 2) * 128 + c0]);
    float4 w3 = *reinterpret_cast<const float4*>(&W[(k0 + 3) * 128 + c0]);
#pragma unroll
    for (int r = 0; r < 8; ++r) {
      float4 a = *reinterpret_cast<const float4*>(&Ar[r * 128 + k0]);
      acc[r][0] += a.x * w0.x + a.y * w1.x + a.z * w2.x + a.w * w3.x;
      acc[r][1] += a.x * w0.y + a.y * w1.y + a.z * w2.y + a.w * w3.y;
      acc[r][2] += a.x * w0.z + a.y * w1.z + a.z * w2.z + a.w * w3.z;
      acc[r][3] += a.x * w0.w + a.y * w1.w + a.z * w2.w + a.w * w3.w;
    }
  }
  const float4 bc = *reinterpret_cast<const float4*>(&b[c0]);
#pragma unroll
  for (int r = 0; r < 8; ++r) {
    const int row = brow + tr * 8 + r;
    const float di = dinv[row];
    float4 o;
    o.x = (acc[r][0] + bc.x) * di;
    o.y = (acc[r][1] + bc.y) * di;
    o.z = (acc[r][2] + bc.z) * di;
    o.w = (acc[r][3] + bc.w) * di;
    *reinterpret_cast<float4*>(&y[(size_t)row * 128 + c0]) = o;
  }
}

// ======== x_new[t] = dinv[t] * (y[t] + sum_{s->t} y[s])  (CSR gather) =======
__global__ __launch_bounds__(256) void k_gather_x(
    const int* __restrict__ rp, const int* __restrict__ cnt,
    const int* __restrict__ lst, const float* __restrict__ y,
    const float* __restrict__ dinv, float* __restrict__ xnew) {
  const int row = blockIdx.x * 8 + (threadIdx.x >> 5);
  const int c = (threadIdx.x & 31) << 2;
  float4 acc = *reinterpret_cast<const float4*>(y + (size_t)row * 128 + c);
  const int start = rp[row];
  const int deg = cnt[row];
  int s = (deg > 0) ? lst[start] : 0;
  for (int j = 0; j < deg; ++j) {
    const int sn = (j + 1 < deg) ? lst[start + j + 1] : 0;
    const float4 v = *reinterpret_cast<const float4*>(y + (size_t)s * 128 + c);
    acc.x += v.x; acc.y += v.y; acc.z += v.z; acc.w += v.w;
    s = sn;
  }
  const float dt = dinv[row];
  acc.x *= dt; acc.y *= dt; acc.z *= dt; acc.w *= dt;
  *reinterpret_cast<float4*>(xnew + (size_t)row * 128 + c) = acc;
}

// ======== ff[f] = sum_{atoms i in f} xnew[i]  (CSR gather) ==================
__global__ __launch_bounds__(256) void k_gather_ff(
    const int* __restrict__ rp, const int* __restrict__ cnt,
    const int* __restrict__ lst, const float* __restrict__ xnew,
    float* __restrict__ ff) {
  const int f = blockIdx.x * 8 + (threadIdx.x >> 5);
  const int c = (threadIdx.x & 31) << 2;
  float4 acc = {0.f, 0.f, 0.f, 0.f};
  const int start = rp[f];
  const int deg = cnt[f];
  int s = (deg > 0) ? lst[start] : 0;
  for (int j = 0; j < deg; ++j) {
    const int sn = (j + 1 < deg) ? lst[start + j + 1] : 0;
    const float4 v = *reinterpret_cast<const float4*>(xnew + (size_t)s * 128 + c);
    acc.x += v.x; acc.y += v.y; acc.z += v.z; acc.w += v.w;
    s = sn;
  }
  *reinterpret_cast<float4*>(ff + (size_t)f * 128 + c) = acc;
}

// ======== fused: fsum gather (frag edges) + 2-layer MLP =====================
// Block = 32 frag rows. Stage fsum rows into LDS via CSR gather, then
// register-tiled GEMM1 (relu) -> hs LDS -> GEMM2 -> out.
__global__ __launch_bounds__(256) void k_mlp(
    const int* __restrict__ rp, const int* __restrict__ cnt,
    const int* __restrict__ lst, const float* __restrict__ ff,
    const float* __restrict__ W1, const float* __restrict__ b1,
    const float* __restrict__ W2, const float* __restrict__ b2,
    float* __restrict__ out) {
  __shared__ float As[32][128];
  __shared__ float hs[32][256];
  const int row0 = blockIdx.x * 32;
  {  // gather: 8 groups x 32 lanes; each group handles 4 rows
    const int g = threadIdx.x >> 5;
    const int c = (threadIdx.x & 31) << 2;
#pragma unroll
    for (int rr = 0; rr < 4; ++rr) {
      const int f = row0 + g * 4 + rr;
      const int start = rp[f];
      const int deg = cnt[f];
      float4 acc = {0.f, 0.f, 0.f, 0.f};
      for (int j = 0; j < deg; ++j) {
        const int s = lst[start + j];
        const float4 v = *reinterpret_cast<const float4*>(ff + (size_t)s * 128 + c);
        acc.x += v.x; acc.y += v.y; acc.z += v.z; acc.w += v.w;
      }
      *reinterpret_cast<float4*>(&As[g * 4 + rr][c]) = acc;
    }
  }
  __syncthreads();
  {  // GEMM1: tc=tid&63 -> c0 of 256; tr=tid>>6 -> rows tr*8..+7
    const int tc = threadIdx.x & 63;
    const int tr = threadIdx.x >> 6;
    const int c0 = tc * 4;
    float acc[8][4] = {};
    for (int k0 = 0; k0 < 128; k0 += 4) {
      float4 w0 = *reinterpret_cast<const float4*>(&W1[(k0 + 0) * 256 + c0]);
      float4 w1 = *reinterpret_cast<const float4*>(&W1[(k0 + 1) * 256 + c0]);
      float4 w2 = *reinterpret_cast<const float4*>(&W1[(k0 + 2) * 256 + c0]);
      float4 w3 = *reinterpret_cast<const float4*>(&W1[(k0 + 3) * 256 + c0]);
#pragma unroll
      for (int r = 0; r < 8; ++r) {
        float4 a = *reinterpret_cast<const float4*>(&As[tr * 8 + r][k0]);
        acc[r][0] += a.x * w0.x + a.y * w1.x + a.z * w2.x + a.w * w3.x;
        acc[r][1] += a.x * w0.y + a.y * w1.y + a.z * w2.y + a.w * w3.y;
        acc[r][2] += a.x * w0.z + a.y * w1.z + a.z * w2.z + a.w * w3.z;
        acc[r][3] += a.x * w0.w + a.y * w1.w + a.z * w2.w + a.w * w3.w;
      }
    }
    const float4 bc = *reinterpret_cast<const float4*>(&b1[c0]);
#pragma unroll
    for (int r = 0; r < 8; ++r) {
      float4 h;
      h.x = fmaxf(acc[r][0] + bc.x, 0.f);
      h.y = fmaxf(acc[r][1] + bc.y, 0.f);
      h.z = fmaxf(acc[r][2] + bc.z, 0.f);
      h.w = fmaxf(acc[r][3] + bc.w, 0.f);
      *reinterpret_cast<float4*>(&hs[tr * 8 + r][c0]) = h;
    }
  }
  __syncthreads();
  {  // GEMM2: tc=tid&31 -> c0 of 128; tr=tid>>5 -> rows tr*4..+3
    const int tc = threadIdx.x & 31;
    const int tr = threadIdx.x >> 5;
    const int c0 = tc * 4;
    float acc[4][4] = {};
    for (int k0 = 0; k0 < 256; k0 += 4) {
      float4 w0 = *reinterpret_cast<const float4*>(&W2[(k0 + 0) * 128 + c0]);
      float4 w1 = *reinterpret_cast<const float4*>(&W2[(k0 + 1) * 128 + c0]);
      float4 w2 = *reinterpret_cast<const float4*>(&W2[(k0 + 2) * 128 + c0]);
      float4 w3 = *reinterpret_cast<const float4*>(&W2[(k0 + 3) * 128 + c0]);
#pragma unroll
      for (int r = 0; r < 4; ++r) {
        float4 a = *reinterpret_cast<const float4*>(&hs[tr * 4 + r][k0]);
        acc[r][0] += a.x * w0.x + a.y * w1.x + a.z * w2.x + a.w * w3.x;
        acc[r][1] += a.x * w0.y + a.y * w1.y + a.z * w2.y + a.w * w3.y;
        acc[r][2] += a.x * w0.z + a.y * w1.z + a.z * w2.z + a.w * w3.z;
        acc[r][3] += a.x * w0.w + a.y * w1.w + a.z * w2.w + a.w * w3.w;
      }
    }
    const float4 bc = *reinterpret_cast<const float4*>(&b2[c0]);
#pragma unroll
    for (int r = 0; r < 4; ++r) {
      float4 o;
      o.x = acc[r][0] + bc.x;
      o.y = acc[r][1] + bc.y;
      o.z = acc[r][2] + bc.z;
      o.w = acc[r][3] + bc.w;
      *reinterpret_cast<float4*>(&out[(size_t)(row0 + tr * 4 + r) * 128 + c0]) = o;
    }
  }
}

extern "C" void kernel_launch(void* const* d_in, const int* in_sizes, int n_in,
                              void* d_out, int out_size, void* d_ws, size_t ws_size,
                              hipStream_t stream) {
  // Bond-graph GAT inputs are dead code w.r.t. the returned outputs.
  const float* x_atoms    = (const float*)d_in[0];
  const int*   edge_index = (const int*)d_in[1];
  const int*   frag_index = (const int*)d_in[3];
  const int*   a2f        = (const int*)d_in[5];
  const float* W_atom     = (const float*)d_in[9];
  const float* b_atom     = (const float*)d_in[10];
  const float* W_f1       = (const float*)d_in[16];
  const float* b_f1       = (const float*)d_in[17];
  const float* W_f2       = (const float*)d_in[18];
  const float* b_f2       = (const float*)d_in[19];

  char* ws = (char*)d_ws;
  size_t off = 0;
  auto alloc = [&](size_t bytes) {
    void* p = ws + off;
    off += (bytes + 255) & ~(size_t)255;
    return p;
  };
  // --- zeroed-each-call pool ---
  int* cnt_src = (int*)alloc((size_t)NA * 4);
  int* cnt_all = (int*)alloc((size_t)NSEG * 4);
  int* cur_all = (int*)alloc((size_t)NSEG * 4);
  const size_t zero_bytes = off;
  // --- rebuilt-each-call ---
  int* rp_all = (int*)alloc(((size_t)NSEG + 1) * 4);
  int* bsum   = (int*)alloc(1024 * 4);
  int* lst    = (int*)alloc((size_t)TOTW * 4);
  float* dinv = (float*)alloc((size_t)NA * 4);
  float* y    = (float*)alloc((size_t)NA * 128 * 4);
  float* ff   = (float*)alloc((size_t)NF * 128 * 4);

  float* xnew = (float*)d_out;                     // [NA,128]
  float* fout = (float*)d_out + (size_t)NA * 128;  // [NF,128]

  hipMemsetAsync(ws, 0, zero_bytes, stream);

  k_hist_all<<<(TOTW + 255) / 256, 256, 0, stream>>>(edge_index, a2f, frag_index,
                                                     cnt_src, cnt_all);
  {
    int nb = (NSEG + 1023) / 1024;  // 235
    k_scan1<<<nb, 256, 0, stream>>>(cnt_all, rp_all, bsum, NSEG);
    k_scan2<<<1, 1024, 0, stream>>>(bsum, nb);
    k_scan3<<<(NSEG + 255) / 256, 256, 0, stream>>>(rp_all, bsum, cnt_src, dinv, NSEG);
  }
  k_fill_all<<<(TOTW + 255) / 256, 256, 0, stream>>>(edge_index, a2f, frag_index,
                                                     rp_all, cur_all, lst);

  k_gemm_y  <<<NA / 64, 256, 0, stream>>>(x_atoms, W_atom, b_atom, dinv, y);
  k_gather_x<<<NA / 8, 256, 0, stream>>>(rp_all, cnt_all, lst, y, dinv, xnew);
  k_gather_ff<<<NF / 8, 256, 0, stream>>>(rp_all + NA, cnt_all + NA, lst, xnew, ff);
  k_mlp     <<<NF / 32, 256, 0, stream>>>(rp_all + NA + NF, cnt_all + NA + NF, lst,
                                          ff, W_f1, b_f1, W_f2, b_f2, fout);
}

// Round 5
// 406.208 us; speedup vs baseline: 5.9145x; 1.0841x over previous
//
#include <hip/hip_runtime.h>
#include <hip/hip_bf16.h>
#include <cstddef>

#define NA 200000   // atoms
#define EA 800000   // atom-graph edges
#define NF 20000    // fragments
#define EF 60000    // fragment-graph edges
// D = 128, hidden = 256
#define NSEG (NA + 2 * NF)          // concatenated count array length (240000)
#define TOTW (EA + NA + EF)         // fused hist/fill work items (1060000)

typedef unsigned short ushort_t;

__device__ __forceinline__ unsigned short f2bf(float f) {
  unsigned u = __builtin_bit_cast(unsigned, f);
  u += 0x7FFFu + ((u >> 16) & 1u);  // round-to-nearest-even
  return (unsigned short)(u >> 16);
}
__device__ __forceinline__ float bf2f(unsigned short h) {
  unsigned u = ((unsigned)h) << 16;
  return __builtin_bit_cast(float, u);
}

// ================= fused histogram ==========================================
// cnt_src[i]: out-degree over edge_index[0] (for dinv)
// cnt_all:   [cnt_e by tgt (NA) | cnt_a by frag (NF) | cnt_f by ft (NF)]
__global__ __launch_bounds__(256) void k_hist_all(
    const int* __restrict__ ei, const int* __restrict__ a2f,
    const int* __restrict__ fi, int* __restrict__ cnt_src,
    int* __restrict__ cnt_all) {
  int idx = blockIdx.x * 256 + threadIdx.x;
  if (idx < EA) {
    atomicAdd(&cnt_src[ei[idx]], 1);
    atomicAdd(&cnt_all[ei[EA + idx]], 1);
  } else if (idx < EA + NA) {
    atomicAdd(&cnt_all[NA + a2f[idx - EA]], 1);
  } else if (idx < TOTW) {
    atomicAdd(&cnt_all[NA + NF + fi[EF + (idx - EA - NA)]], 1);
  }
}

// ================= exclusive scan over cnt_all (global; 3 kernels) ==========
__global__ __launch_bounds__(256) void k_scan1(const int* __restrict__ cnt,
                                               int* __restrict__ rp,
                                               int* __restrict__ bsum, int n) {
  __shared__ int sh[256];
  const int base = blockIdx.x * 1024;
  const int tid = threadIdx.x;
  int v[4], s = 0;
#pragma unroll
  for (int j = 0; j < 4; ++j) {
    int idx = base + tid * 4 + j;
    v[j] = (idx < n) ? cnt[idx] : 0;
    s += v[j];
  }
  sh[tid] = s;
  __syncthreads();
  for (int off = 1; off < 256; off <<= 1) {
    int t = (tid >= off) ? sh[tid - off] : 0;
    __syncthreads();
    sh[tid] += t;
    __syncthreads();
  }
  int excl = (tid > 0) ? sh[tid - 1] : 0;
#pragma unroll
  for (int j = 0; j < 4; ++j) {
    int idx = base + tid * 4 + j;
    if (idx < n) rp[idx] = excl;
    excl += v[j];
  }
  if (tid == 255) bsum[blockIdx.x] = sh[255];
}
__global__ __launch_bounds__(1024) void k_scan2(int* __restrict__ bsum, int nb) {
  __shared__ int sh[1024];
  const int tid = threadIdx.x;
  sh[tid] = (tid < nb) ? bsum[tid] : 0;
  __syncthreads();
  for (int off = 1; off < 1024; off <<= 1) {
    int t = (tid >= off) ? sh[tid - off] : 0;
    __syncthreads();
    sh[tid] += t;
    __syncthreads();
  }
  if (tid < nb) bsum[tid] = (tid > 0) ? sh[tid - 1] : 0;  // exclusive
}
// + fused dinv = rsqrt(1 + out-degree)
__global__ __launch_bounds__(256) void k_scan3(int* __restrict__ rp,
                                               const int* __restrict__ bsum,
                                               const int* __restrict__ cnt_src,
                                               float* __restrict__ dinv, int n) {
  int i = blockIdx.x * 256 + threadIdx.x;
  if (i < n) rp[i] += bsum[i >> 10];
  if (i < NA) dinv[i] = rsqrtf((float)(1 + cnt_src[i]));
}

// ================= fused CSR fill ===========================================
__global__ __launch_bounds__(256) void k_fill_all(
    const int* __restrict__ ei, const int* __restrict__ a2f,
    const int* __restrict__ fi, const int* __restrict__ rp,
    int* __restrict__ cur, int* __restrict__ lst) {
  int idx = blockIdx.x * 256 + threadIdx.x;
  if (idx < EA) {
    int t = ei[EA + idx];
    int p = atomicAdd(&cur[t], 1);
    lst[rp[t] + p] = ei[idx];            // src atom
  } else if (idx < EA + NA) {
    int i = idx - EA;
    int f = NA + a2f[i];
    int p = atomicAdd(&cur[f], 1);
    lst[rp[f] + p] = i;                  // atom id
  } else if (idx < TOTW) {
    int e = idx - EA - NA;
    int t = NA + NF + fi[EF + e];
    int p = atomicAdd(&cur[t], 1);
    lst[rp[t] + p] = fi[e];              // fs
  }
}

// ======== y = bf16( (x_atoms @ W_atom + b_atom) * dinv[row] ) ===============
// Block = 64 rows x 128 cols; A tile (32 KB) bulk-staged into LDS; W loads
// double-buffered in registers so L2 latency hides under the FMA burst.
__global__ __launch_bounds__(256) void k_gemm_y(
    const float* __restrict__ xa, const float* __restrict__ W,
    const float* __restrict__ b, const float* __restrict__ dinv,
    ushort_t* __restrict__ y) {
  __shared__ float As[64 * 128];
  const int tid = threadIdx.x;
  const int brow = blockIdx.x * 64;
  {
    const float4* gA = reinterpret_cast<const float4*>(xa + (size_t)brow * 128);
    float4 st[8];
#pragma unroll
    for (int i = 0; i < 8; ++i) st[i] = gA[tid + i * 256];
#pragma unroll
    for (int i = 0; i < 8; ++i)
      reinterpret_cast<float4*>(As)[tid + i * 256] = st[i];
  }
  __syncthreads();
  const int tc = tid & 31;
  const int tr = tid >> 5;
  const int c0 = tc * 4;
  const float* Ar = As + (tr * 8) * 128;
  float acc[8][4] = {};
  float4 wc[4], wn[4];
#pragma unroll
  for (int j = 0; j < 4; ++j)
    wc[j] = *reinterpret_cast<const float4*>(&W[j * 128 + c0]);
#pragma unroll 2
  for (int k0 = 0; k0 < 128; k0 += 4) {
    if (k0 + 4 < 128) {
#pragma unroll
      for (int j = 0; j < 4; ++j)
        wn[j] = *reinterpret_cast<const float4*>(&W[(k0 + 4 + j) * 128 + c0]);
    }
#pragma unroll
    for (int r = 0; r < 8; ++r) {
      float4 a = *reinterpret_cast<const float4*>(&Ar[r * 128 + k0]);
      acc[r][0] += a.x * wc[0].x + a.y * wc[1].x + a.z * wc[2].x + a.w * wc[3].x;
      acc[r][1] += a.x * wc[0].y + a.y * wc[1].y + a.z * wc[2].y + a.w * wc[3].y;
      acc[r][2] += a.x * wc[0].z + a.y * wc[1].z + a.z * wc[2].z + a.w * wc[3].z;
      acc[r][3] += a.x * wc[0].w + a.y * wc[1].w + a.z * wc[2].w + a.w * wc[3].w;
    }
#pragma unroll
    for (int j = 0; j < 4; ++j) wc[j] = wn[j];
  }
  const float4 bc = *reinterpret_cast<const float4*>(&b[c0]);
#pragma unroll
  for (int r = 0; r < 8; ++r) {
    const int row = brow + tr * 8 + r;
    const float di = dinv[row];
    ushort4 o;
    o.x = f2bf((acc[r][0] + bc.x) * di);
    o.y = f2bf((acc[r][1] + bc.y) * di);
    o.z = f2bf((acc[r][2] + bc.z) * di);
    o.w = f2bf((acc[r][3] + bc.w) * di);
    *reinterpret_cast<ushort4*>(&y[(size_t)row * 128 + c0]) = o;
  }
}

// ======== x_new[t] = dinv[t] * (y[t] + sum_{s->t} y[s])  (CSR gather) =======
// y rows are bf16 (256 B); accumulate fp32; write fp32 output.
__global__ __launch_bounds__(256) void k_gather_x(
    const int* __restrict__ rp, const int* __restrict__ cnt,
    const int* __restrict__ lst, const ushort_t* __restrict__ y,
    const float* __restrict__ dinv, float* __restrict__ xnew) {
  const int row = blockIdx.x * 8 + (threadIdx.x >> 5);
  const int c = (threadIdx.x & 31) << 2;
  const ushort4 vs = *reinterpret_cast<const ushort4*>(y + (size_t)row * 128 + c);
  float4 acc = {bf2f(vs.x), bf2f(vs.y), bf2f(vs.z), bf2f(vs.w)};
  const int start = rp[row];
  const int deg = cnt[row];
  int s = (deg > 0) ? lst[start] : 0;
  for (int j = 0; j < deg; ++j) {
    const int sn = (j + 1 < deg) ? lst[start + j + 1] : 0;
    const ushort4 v = *reinterpret_cast<const ushort4*>(y + (size_t)s * 128 + c);
    acc.x += bf2f(v.x); acc.y += bf2f(v.y); acc.z += bf2f(v.z); acc.w += bf2f(v.w);
    s = sn;
  }
  const float dt = dinv[row];
  acc.x *= dt; acc.y *= dt; acc.z *= dt; acc.w *= dt;
  *reinterpret_cast<float4*>(xnew + (size_t)row * 128 + c) = acc;
}

// ======== ff[f] = sum_{atoms i in f} xnew[i]  (CSR gather) ==================
__global__ __launch_bounds__(256) void k_gather_ff(
    const int* __restrict__ rp, const int* __restrict__ cnt,
    const int* __restrict__ lst, const float* __restrict__ xnew,
    float* __restrict__ ff) {
  const int f = blockIdx.x * 8 + (threadIdx.x >> 5);
  const int c = (threadIdx.x & 31) << 2;
  float4 acc = {0.f, 0.f, 0.f, 0.f};
  const int start = rp[f];
  const int deg = cnt[f];
  int s = (deg > 0) ? lst[start] : 0;
  for (int j = 0; j < deg; ++j) {
    const int sn = (j + 1 < deg) ? lst[start + j + 1] : 0;
    const float4 v = *reinterpret_cast<const float4*>(xnew + (size_t)s * 128 + c);
    acc.x += v.x; acc.y += v.y; acc.z += v.z; acc.w += v.w;
    s = sn;
  }
  *reinterpret_cast<float4*>(ff + (size_t)f * 128 + c) = acc;
}

// ======== fused: fsum gather (frag edges) + 2-layer MLP =====================
__global__ __launch_bounds__(256) void k_mlp(
    const int* __restrict__ rp, const int* __restrict__ cnt,
    const int* __restrict__ lst, const float* __restrict__ ff,
    const float* __restrict__ W1, const float* __restrict__ b1,
    const float* __restrict__ W2, const float* __restrict__ b2,
    float* __restrict__ out) {
  __shared__ float As[32][128];
  __shared__ float hs[32][256];
  const int row0 = blockIdx.x * 32;
  {  // gather: 8 groups x 32 lanes; each group handles 4 rows
    const int g = threadIdx.x >> 5;
    const int c = (threadIdx.x & 31) << 2;
#pragma unroll
    for (int rr = 0; rr < 4; ++rr) {
      const int f = row0 + g * 4 + rr;
      const int start = rp[f];
      const int deg = cnt[f];
      float4 acc = {0.f, 0.f, 0.f, 0.f};
      for (int j = 0; j < deg; ++j) {
        const int s = lst[start + j];
        const float4 v = *reinterpret_cast<const float4*>(ff + (size_t)s * 128 + c);
        acc.x += v.x; acc.y += v.y; acc.z += v.z; acc.w += v.w;
      }
      *reinterpret_cast<float4*>(&As[g * 4 + rr][c]) = acc;
    }
  }
  __syncthreads();
  {  // GEMM1: tc=tid&63 -> c0 of 256; tr=tid>>6 -> rows tr*8..+7
    const int tc = threadIdx.x & 63;
    const int tr = threadIdx.x >> 6;
    const int c0 = tc * 4;
    float acc[8][4] = {};
    for (int k0 = 0; k0 < 128; k0 += 4) {
      float4 w0 = *reinterpret_cast<const float4*>(&W1[(k0 + 0) * 256 + c0]);
      float4 w1 = *reinterpret_cast<const float4*>(&W1[(k0 + 1) * 256 + c0]);
      float4 w2 = *reinterpret_cast<const float4*>(&W1[(k0 + 2) * 256 + c0]);
      float4 w3 = *reinterpret_cast<const float4*>(&W1[(k0 + 3) * 256 + c0]);
#pragma unroll
      for (int r = 0; r < 8; ++r) {
        float4 a = *reinterpret_cast<const float4*>(&As[tr * 8 + r][k0]);
        acc[r][0] += a.x * w0.x + a.y * w1.x + a.z * w2.x + a.w * w3.x;
        acc[r][1] += a.x * w0.y + a.y * w1.y + a.z * w2.y + a.w * w3.y;
        acc[r][2] += a.x * w0.z + a.y * w1.z + a.z * w2.z + a.w * w3.z;
        acc[r][3] += a.x * w0.w + a.y * w1.w + a.z * w2.w + a.w * w3.w;
      }
    }
    const float4 bc = *reinterpret_cast<const float4*>(&b1[c0]);
#pragma unroll
    for (int r = 0; r < 8; ++r) {
      float4 h;
      h.x = fmaxf(acc[r][0] + bc.x, 0.f);
      h.y = fmaxf(acc[r][1] + bc.y, 0.f);
      h.z = fmaxf(acc[r][2] + bc.z, 0.f);
      h.w = fmaxf(acc[r][3] + bc.w, 0.f);
      *reinterpret_cast<float4*>(&hs[tr * 8 + r][c0]) = h;
    }
  }
  __syncthreads();
  {  // GEMM2: tc=tid&31 -> c0 of 128; tr=tid>>5 -> rows tr*4..+3
    const int tc = threadIdx.x & 31;
    const int tr = threadIdx.x >> 5;
    const int c0 = tc * 4;
    float acc[4][4] = {};
    for (int k0 = 0; k0 < 256; k0 += 4) {
      float4 w0 = *reinterpret_cast<const float4*>(&W2[(k0 + 0) * 128 + c0]);
      float4 w1 = *reinterpret_cast<const float4*>(&W2[(k0 + 1) * 128 + c0]);
      float4 w2 = *reinterpret_cast<const float4*>(&W2[(k0 + 2) * 128 + c0]);
      float4 w3 = *reinterpret_cast<const float4*>(&W2[(k0 + 3) * 128 + c0]);
#pragma unroll
      for (int r = 0; r < 4; ++r) {
        float4 a = *reinterpret_cast<const float4*>(&hs[tr * 4 + r][k0]);
        acc[r][0] += a.x * w0.x + a.y * w1.x + a.z * w2.x + a.w * w3.x;
        acc[r][1] += a.x * w0.y + a.y * w1.y + a.z * w2.y + a.w * w3.y;
        acc[r][2] += a.x * w0.z + a.y * w1.z + a.z * w2.z + a.w * w3.z;
        acc[r][3] += a.x * w0.w + a.y * w1.w + a.z * w2.w + a.w * w3.w;
      }
    }
    const float4 bc = *reinterpret_cast<const float4*>(&b2[c0]);
#pragma unroll
    for (int r = 0; r < 4; ++r) {
      float4 o;
      o.x = acc[r][0] + bc.x;
      o.y = acc[r][1] + bc.y;
      o.z = acc[r][2] + bc.z;
      o.w = acc[r][3] + bc.w;
      *reinterpret_cast<float4*>(&out[(size_t)(row0 + tr * 4 + r) * 128 + c0]) = o;
    }
  }
}

extern "C" void kernel_launch(void* const* d_in, const int* in_sizes, int n_in,
                              void* d_out, int out_size, void* d_ws, size_t ws_size,
                              hipStream_t stream) {
  // Bond-graph GAT inputs are dead code w.r.t. the returned outputs.
  const float* x_atoms    = (const float*)d_in[0];
  const int*   edge_index = (const int*)d_in[1];
  const int*   frag_index = (const int*)d_in[3];
  const int*   a2f        = (const int*)d_in[5];
  const float* W_atom     = (const float*)d_in[9];
  const float* b_atom     = (const float*)d_in[10];
  const float* W_f1       = (const float*)d_in[16];
  const float* b_f1       = (const float*)d_in[17];
  const float* W_f2       = (const float*)d_in[18];
  const float* b_f2       = (const float*)d_in[19];

  char* ws = (char*)d_ws;
  size_t off = 0;
  auto alloc = [&](size_t bytes) {
    void* p = ws + off;
    off += (bytes + 255) & ~(size_t)255;
    return p;
  };
  // --- zeroed-each-call pool ---
  int* cnt_src = (int*)alloc((size_t)NA * 4);
  int* cnt_all = (int*)alloc((size_t)NSEG * 4);
  int* cur_all = (int*)alloc((size_t)NSEG * 4);
  const size_t zero_bytes = off;
  // --- rebuilt-each-call ---
  int* rp_all = (int*)alloc(((size_t)NSEG + 1) * 4);
  int* bsum   = (int*)alloc(1024 * 4);
  int* lst    = (int*)alloc((size_t)TOTW * 4);
  float* dinv = (float*)alloc((size_t)NA * 4);
  ushort_t* y = (ushort_t*)alloc((size_t)NA * 128 * 2);  // bf16
  float* ff   = (float*)alloc((size_t)NF * 128 * 4);

  float* xnew = (float*)d_out;                     // [NA,128]
  float* fout = (float*)d_out + (size_t)NA * 128;  // [NF,128]

  hipMemsetAsync(ws, 0, zero_bytes, stream);

  k_hist_all<<<(TOTW + 255) / 256, 256, 0, stream>>>(edge_index, a2f, frag_index,
                                                     cnt_src, cnt_all);
  {
    int nb = (NSEG + 1023) / 1024;  // 235
    k_scan1<<<nb, 256, 0, stream>>>(cnt_all, rp_all, bsum, NSEG);
    k_scan2<<<1, 1024, 0, stream>>>(bsum, nb);
    k_scan3<<<(NSEG + 255) / 256, 256, 0, stream>>>(rp_all, bsum, cnt_src, dinv, NSEG);
  }
  k_fill_all<<<(TOTW + 255) / 256, 256, 0, stream>>>(edge_index, a2f, frag_index,
                                                     rp_all, cur_all, lst);

  k_gemm_y  <<<NA / 64, 256, 0, stream>>>(x_atoms, W_atom, b_atom, dinv, y);
  k_gather_x<<<NA / 8, 256, 0, stream>>>(rp_all, cnt_all, lst, y, dinv, xnew);
  k_gather_ff<<<NF / 8, 256, 0, stream>>>(rp_all + NA, cnt_all + NA, lst, xnew, ff);
  k_mlp     <<<NF / 32, 256, 0, stream>>>(rp_all + NA + NF, cnt_all + NA + NF, lst,
                                          ff, W_f1, b_f1, W_f2, b_f2, fout);
}

// Round 6
// 335.802 us; speedup vs baseline: 7.1545x; 1.2097x over previous
//
#include <hip/hip_runtime.h>
#include <hip/hip_bf16.h>
#include <cstddef>

#define NA 200000   // atoms
#define EA 800000   // atom-graph edges
#define NF 20000    // fragments
#define EF 60000    // fragment-graph edges
// D = 128, hidden = 256
#define NSEG (NA + 2 * NF)          // concatenated count array length (240000)
#define TOTW (EA + NA + EF)         // fused hist/fill work items (1060000)

typedef unsigned short ushort_t;
typedef __attribute__((ext_vector_type(8))) short bf16x8;
typedef __attribute__((ext_vector_type(4))) float f32x4;

__device__ __forceinline__ unsigned short f2bf(float f) {
  unsigned u = __builtin_bit_cast(unsigned, f);
  u += 0x7FFFu + ((u >> 16) & 1u);  // round-to-nearest-even
  return (unsigned short)(u >> 16);
}
__device__ __forceinline__ float bf2f(unsigned short h) {
  unsigned u = ((unsigned)h) << 16;
  return __builtin_bit_cast(float, u);
}

// ================= fused histogram ==========================================
__global__ __launch_bounds__(256) void k_hist_all(
    const int* __restrict__ ei, const int* __restrict__ a2f,
    const int* __restrict__ fi, int* __restrict__ cnt_src,
    int* __restrict__ cnt_all) {
  int idx = blockIdx.x * 256 + threadIdx.x;
  if (idx < EA) {
    atomicAdd(&cnt_src[ei[idx]], 1);
    atomicAdd(&cnt_all[ei[EA + idx]], 1);
  } else if (idx < EA + NA) {
    atomicAdd(&cnt_all[NA + a2f[idx - EA]], 1);
  } else if (idx < TOTW) {
    atomicAdd(&cnt_all[NA + NF + fi[EF + (idx - EA - NA)]], 1);
  }
}

// ================= exclusive scan over cnt_all ==============================
__global__ __launch_bounds__(256) void k_scan1(const int* __restrict__ cnt,
                                               int* __restrict__ rp,
                                               int* __restrict__ bsum, int n) {
  __shared__ int sh[256];
  const int base = blockIdx.x * 1024;
  const int tid = threadIdx.x;
  int v[4], s = 0;
#pragma unroll
  for (int j = 0; j < 4; ++j) {
    int idx = base + tid * 4 + j;
    v[j] = (idx < n) ? cnt[idx] : 0;
    s += v[j];
  }
  sh[tid] = s;
  __syncthreads();
  for (int off = 1; off < 256; off <<= 1) {
    int t = (tid >= off) ? sh[tid - off] : 0;
    __syncthreads();
    sh[tid] += t;
    __syncthreads();
  }
  int excl = (tid > 0) ? sh[tid - 1] : 0;
#pragma unroll
  for (int j = 0; j < 4; ++j) {
    int idx = base + tid * 4 + j;
    if (idx < n) rp[idx] = excl;
    excl += v[j];
  }
  if (tid == 255) bsum[blockIdx.x] = sh[255];
}
__global__ __launch_bounds__(1024) void k_scan2(int* __restrict__ bsum, int nb) {
  __shared__ int sh[1024];
  const int tid = threadIdx.x;
  sh[tid] = (tid < nb) ? bsum[tid] : 0;
  __syncthreads();
  for (int off = 1; off < 1024; off <<= 1) {
    int t = (tid >= off) ? sh[tid - off] : 0;
    __syncthreads();
    sh[tid] += t;
    __syncthreads();
  }
  if (tid < nb) bsum[tid] = (tid > 0) ? sh[tid - 1] : 0;  // exclusive
}
// + fused dinv = rsqrt(1 + out-degree)
__global__ __launch_bounds__(256) void k_scan3(int* __restrict__ rp,
                                               const int* __restrict__ bsum,
                                               const int* __restrict__ cnt_src,
                                               float* __restrict__ dinv, int n) {
  int i = blockIdx.x * 256 + threadIdx.x;
  if (i < n) rp[i] += bsum[i >> 10];
  if (i < NA) dinv[i] = rsqrtf((float)(1 + cnt_src[i]));
}

// ================= fused CSR fill ===========================================
__global__ __launch_bounds__(256) void k_fill_all(
    const int* __restrict__ ei, const int* __restrict__ a2f,
    const int* __restrict__ fi, const int* __restrict__ rp,
    int* __restrict__ cur, int* __restrict__ lst) {
  int idx = blockIdx.x * 256 + threadIdx.x;
  if (idx < EA) {
    int t = ei[EA + idx];
    int p = atomicAdd(&cur[t], 1);
    lst[rp[t] + p] = ei[idx];            // src atom
  } else if (idx < EA + NA) {
    int i = idx - EA;
    int f = NA + a2f[i];
    int p = atomicAdd(&cur[f], 1);
    lst[rp[f] + p] = i;                  // atom id
  } else if (idx < TOTW) {
    int e = idx - EA - NA;
    int t = NA + NF + fi[EF + e];
    int p = atomicAdd(&cur[t], 1);
    lst[rp[t] + p] = fi[e];              // fs
  }
}

// ======== Wt[c][k] = bf16(W[k][c]) — tiny precompute ========================
__global__ __launch_bounds__(256) void k_wt(const float* __restrict__ W,
                                            ushort_t* __restrict__ Wt) {
  int idx = blockIdx.x * 256 + threadIdx.x;  // 16384
  if (idx < 128 * 128) {
    int c = idx >> 7, k = idx & 127;
    Wt[idx] = f2bf(W[k * 128 + c]);
  }
}

// ======== y = bf16( (x_atoms @ W_atom + b_atom) * dinv[row] ) — MFMA ========
// Block = 64 rows x 128 cols, 256 thr (4 waves). A cast to bf16 in LDS
// (swizzled), Wt staged to LDS (swizzled). Wave w: rows w*16..+15, all 128
// cols = 8 n-tiles x 4 K-steps of mfma_f32_16x16x32_bf16.
// Frag layout: A lane l holds A[l&15][k], k = (l>>4)*4 + j (j=0..3, regs 0-1,
// first K16 half) and +16 (j=4..7, regs 2-3). B symmetric on cols. D: col =
// lane&15, row = (lane>>4)*4 + reg (verified m89 mapping).
__global__ __launch_bounds__(256) void k_gemm_y(
    const float* __restrict__ xa, const ushort_t* __restrict__ Wt,
    const float* __restrict__ b, const float* __restrict__ dinv,
    ushort_t* __restrict__ y) {
  __shared__ ushort_t Asl[64 * 128];   // 16 KB, swizzled bf16 A
  __shared__ ushort_t Bsl[128 * 128];  // 32 KB, swizzled bf16 Wt
  const int tid = threadIdx.x;
  const int brow = blockIdx.x * 64;
  {  // stage A: 2048 float4 units, cvt to bf16, swizzled ds_write (8 B units)
    const float4* gA = reinterpret_cast<const float4*>(xa + (size_t)brow * 128);
#pragma unroll
    for (int i = 0; i < 8; ++i) {
      int f = tid + i * 256;
      int row = f >> 5;            // 0..63
      int kq = f & 31;             // float4 unit within row
      float4 v = gA[f];
      ushort4 u;
      u.x = f2bf(v.x); u.y = f2bf(v.y); u.z = f2bf(v.z); u.w = f2bf(v.w);
      int koff = (kq * 4) ^ ((row & 7) << 3);
      *reinterpret_cast<ushort4*>(&Asl[row * 128 + koff]) = u;
    }
    // stage Wt: 2048 16B units, swizzled
    const uint4* gW = reinterpret_cast<const uint4*>(Wt);
#pragma unroll
    for (int i = 0; i < 8; ++i) {
      int u = tid + i * 256;       // 0..2047
      int c = u >> 4;              // Wt row (=output col), 0..127
      int k8 = u & 15;             // 8-ushort unit within row
      uint4 v = gW[u];
      int koff = (k8 * 8) ^ ((c & 7) << 3);
      *reinterpret_cast<uint4*>(&Bsl[c * 128 + koff]) = v;
    }
  }
  __syncthreads();
  const int w = tid >> 6;
  const int l = tid & 63;
  const int lr = l & 15;
  const int g = l >> 4;
  const int r0 = w * 16;
  f32x4 acc[8] = {};
  const int arow = r0 + lr;
  const int asw = (arow & 7) << 3;
#pragma unroll
  for (int s = 0; s < 4; ++s) {
    const int kb = s * 32 + g * 4;
    ushort4 alo = *reinterpret_cast<const ushort4*>(&Asl[arow * 128 + (kb ^ asw)]);
    ushort4 ahi = *reinterpret_cast<const ushort4*>(&Asl[arow * 128 + ((kb + 16) ^ asw)]);
    bf16x8 a;
    a[0] = (short)alo.x; a[1] = (short)alo.y; a[2] = (short)alo.z; a[3] = (short)alo.w;
    a[4] = (short)ahi.x; a[5] = (short)ahi.y; a[6] = (short)ahi.z; a[7] = (short)ahi.w;
#pragma unroll
    for (int t = 0; t < 8; ++t) {
      const int bc = t * 16 + lr;
      const int bsw = (bc & 7) << 3;
      ushort4 blo = *reinterpret_cast<const ushort4*>(&Bsl[bc * 128 + (kb ^ bsw)]);
      ushort4 bhi = *reinterpret_cast<const ushort4*>(&Bsl[bc * 128 + ((kb + 16) ^ bsw)]);
      bf16x8 bf;
      bf[0] = (short)blo.x; bf[1] = (short)blo.y; bf[2] = (short)blo.z; bf[3] = (short)blo.w;
      bf[4] = (short)bhi.x; bf[5] = (short)bhi.y; bf[6] = (short)bhi.z; bf[7] = (short)bhi.w;
      acc[t] = __builtin_amdgcn_mfma_f32_16x16x32_bf16(a, bf, acc[t], 0, 0, 0);
    }
  }
  float di[4];
#pragma unroll
  for (int r = 0; r < 4; ++r) di[r] = dinv[brow + r0 + g * 4 + r];
#pragma unroll
  for (int t = 0; t < 8; ++t) {
    const int col = t * 16 + lr;
    const float bb = b[col];
#pragma unroll
    for (int r = 0; r < 4; ++r) {
      const int row = brow + r0 + g * 4 + r;
      y[(size_t)row * 128 + col] = f2bf((acc[t][r] + bb) * di[r]);
    }
  }
}

// ======== x_new[t] = dinv[t] * (y[t] + sum_{s->t} y[s])  (CSR gather) =======
__global__ __launch_bounds__(256) void k_gather_x(
    const int* __restrict__ rp, const int* __restrict__ cnt,
    const int* __restrict__ lst, const ushort_t* __restrict__ y,
    const float* __restrict__ dinv, float* __restrict__ xnew) {
  const int row = blockIdx.x * 8 + (threadIdx.x >> 5);
  const int c = (threadIdx.x & 31) << 2;
  const ushort4 vs = *reinterpret_cast<const ushort4*>(y + (size_t)row * 128 + c);
  float4 acc = {bf2f(vs.x), bf2f(vs.y), bf2f(vs.z), bf2f(vs.w)};
  const int start = rp[row];
  const int deg = cnt[row];
  int s = (deg > 0) ? lst[start] : 0;
  for (int j = 0; j < deg; ++j) {
    const int sn = (j + 1 < deg) ? lst[start + j + 1] : 0;
    const ushort4 v = *reinterpret_cast<const ushort4*>(y + (size_t)s * 128 + c);
    acc.x += bf2f(v.x); acc.y += bf2f(v.y); acc.z += bf2f(v.z); acc.w += bf2f(v.w);
    s = sn;
  }
  const float dt = dinv[row];
  acc.x *= dt; acc.y *= dt; acc.z *= dt; acc.w *= dt;
  *reinterpret_cast<float4*>(xnew + (size_t)row * 128 + c) = acc;
}

// ======== ff[f] = sum_{atoms i in f} xnew[i]  (CSR gather) ==================
__global__ __launch_bounds__(256) void k_gather_ff(
    const int* __restrict__ rp, const int* __restrict__ cnt,
    const int* __restrict__ lst, const float* __restrict__ xnew,
    float* __restrict__ ff) {
  const int f = blockIdx.x * 8 + (threadIdx.x >> 5);
  const int c = (threadIdx.x & 31) << 2;
  float4 acc = {0.f, 0.f, 0.f, 0.f};
  const int start = rp[f];
  const int deg = cnt[f];
  int s = (deg > 0) ? lst[start] : 0;
  for (int j = 0; j < deg; ++j) {
    const int sn = (j + 1 < deg) ? lst[start + j + 1] : 0;
    const float4 v = *reinterpret_cast<const float4*>(xnew + (size_t)s * 128 + c);
    acc.x += v.x; acc.y += v.y; acc.z += v.z; acc.w += v.w;
    s = sn;
  }
  *reinterpret_cast<float4*>(ff + (size_t)f * 128 + c) = acc;
}

// ======== fused: fsum gather (frag edges) + 2-layer MLP =====================
__global__ __launch_bounds__(256) void k_mlp(
    const int* __restrict__ rp, const int* __restrict__ cnt,
    const int* __restrict__ lst, const float* __restrict__ ff,
    const float* __restrict__ W1, const float* __restrict__ b1,
    const float* __restrict__ W2, const float* __restrict__ b2,
    float* __restrict__ out) {
  __shared__ float As[32][128];
  __shared__ float hs[32][256];
  const int row0 = blockIdx.x * 32;
  {  // gather: 8 groups x 32 lanes; each group handles 4 rows
    const int g = threadIdx.x >> 5;
    const int c = (threadIdx.x & 31) << 2;
#pragma unroll
    for (int rr = 0; rr < 4; ++rr) {
      const int f = row0 + g * 4 + rr;
      const int start = rp[f];
      const int deg = cnt[f];
      float4 acc = {0.f, 0.f, 0.f, 0.f};
      for (int j = 0; j < deg; ++j) {
        const int s = lst[start + j];
        const float4 v = *reinterpret_cast<const float4*>(ff + (size_t)s * 128 + c);
        acc.x += v.x; acc.y += v.y; acc.z += v.z; acc.w += v.w;
      }
      *reinterpret_cast<float4*>(&As[g * 4 + rr][c]) = acc;
    }
  }
  __syncthreads();
  {  // GEMM1
    const int tc = threadIdx.x & 63;
    const int tr = threadIdx.x >> 6;
    const int c0 = tc * 4;
    float acc[8][4] = {};
    for (int k0 = 0; k0 < 128; k0 += 4) {
      float4 w0 = *reinterpret_cast<const float4*>(&W1[(k0 + 0) * 256 + c0]);
      float4 w1 = *reinterpret_cast<const float4*>(&W1[(k0 + 1) * 256 + c0]);
      float4 w2 = *reinterpret_cast<const float4*>(&W1[(k0 + 2) * 256 + c0]);
      float4 w3 = *reinterpret_cast<const float4*>(&W1[(k0 + 3) * 256 + c0]);
#pragma unroll
      for (int r = 0; r < 8; ++r) {
        float4 a = *reinterpret_cast<const float4*>(&As[tr * 8 + r][k0]);
        acc[r][0] += a.x * w0.x + a.y * w1.x + a.z * w2.x + a.w * w3.x;
        acc[r][1] += a.x * w0.y + a.y * w1.y + a.z * w2.y + a.w * w3.y;
        acc[r][2] += a.x * w0.z + a.y * w1.z + a.z * w2.z + a.w * w3.z;
        acc[r][3] += a.x * w0.w + a.y * w1.w + a.z * w2.w + a.w * w3.w;
      }
    }
    const float4 bc = *reinterpret_cast<const float4*>(&b1[c0]);
#pragma unroll
    for (int r = 0; r < 8; ++r) {
      float4 h;
      h.x = fmaxf(acc[r][0] + bc.x, 0.f);
      h.y = fmaxf(acc[r][1] + bc.y, 0.f);
      h.z = fmaxf(acc[r][2] + bc.z, 0.f);
      h.w = fmaxf(acc[r][3] + bc.w, 0.f);
      *reinterpret_cast<float4*>(&hs[tr * 8 + r][c0]) = h;
    }
  }
  __syncthreads();
  {  // GEMM2
    const int tc = threadIdx.x & 31;
    const int tr = threadIdx.x >> 5;
    const int c0 = tc * 4;
    float acc[4][4] = {};
    for (int k0 = 0; k0 < 256; k0 += 4) {
      float4 w0 = *reinterpret_cast<const float4*>(&W2[(k0 + 0) * 128 + c0]);
      float4 w1 = *reinterpret_cast<const float4*>(&W2[(k0 + 1) * 128 + c0]);
      float4 w2 = *reinterpret_cast<const float4*>(&W2[(k0 + 2) * 128 + c0]);
      float4 w3 = *reinterpret_cast<const float4*>(&W2[(k0 + 3) * 128 + c0]);
#pragma unroll
      for (int r = 0; r < 4; ++r) {
        float4 a = *reinterpret_cast<const float4*>(&hs[tr * 4 + r][k0]);
        acc[r][0] += a.x * w0.x + a.y * w1.x + a.z * w2.x + a.w * w3.x;
        acc[r][1] += a.x * w0.y + a.y * w1.y + a.z * w2.y + a.w * w3.y;
        acc[r][2] += a.x * w0.z + a.y * w1.z + a.z * w2.z + a.w * w3.z;
        acc[r][3] += a.x * w0.w + a.y * w1.w + a.z * w2.w + a.w * w3.w;
      }
    }
    const float4 bc = *reinterpret_cast<const float4*>(&b2[c0]);
#pragma unroll
    for (int r = 0; r < 4; ++r) {
      float4 o;
      o.x = acc[r][0] + bc.x;
      o.y = acc[r][1] + bc.y;
      o.z = acc[r][2] + bc.z;
      o.w = acc[r][3] + bc.w;
      *reinterpret_cast<float4*>(&out[(size_t)(row0 + tr * 4 + r) * 128 + c0]) = o;
    }
  }
}

extern "C" void kernel_launch(void* const* d_in, const int* in_sizes, int n_in,
                              void* d_out, int out_size, void* d_ws, size_t ws_size,
                              hipStream_t stream) {
  // Bond-graph GAT inputs are dead code w.r.t. the returned outputs.
  const float* x_atoms    = (const float*)d_in[0];
  const int*   edge_index = (const int*)d_in[1];
  const int*   frag_index = (const int*)d_in[3];
  const int*   a2f        = (const int*)d_in[5];
  const float* W_atom     = (const float*)d_in[9];
  const float* b_atom     = (const float*)d_in[10];
  const float* W_f1       = (const float*)d_in[16];
  const float* b_f1       = (const float*)d_in[17];
  const float* W_f2       = (const float*)d_in[18];
  const float* b_f2       = (const float*)d_in[19];

  char* ws = (char*)d_ws;
  size_t off = 0;
  auto alloc = [&](size_t bytes) {
    void* p = ws + off;
    off += (bytes + 255) & ~(size_t)255;
    return p;
  };
  // --- zeroed-each-call pool ---
  int* cnt_src = (int*)alloc((size_t)NA * 4);
  int* cnt_all = (int*)alloc((size_t)NSEG * 4);
  int* cur_all = (int*)alloc((size_t)NSEG * 4);
  const size_t zero_bytes = off;
  // --- rebuilt-each-call ---
  int* rp_all = (int*)alloc(((size_t)NSEG + 1) * 4);
  int* bsum   = (int*)alloc(1024 * 4);
  int* lst    = (int*)alloc((size_t)TOTW * 4);
  float* dinv = (float*)alloc((size_t)NA * 4);
  ushort_t* Wt = (ushort_t*)alloc((size_t)128 * 128 * 2);  // bf16 W^T
  ushort_t* y = (ushort_t*)alloc((size_t)NA * 128 * 2);    // bf16
  float* ff   = (float*)alloc((size_t)NF * 128 * 4);

  float* xnew = (float*)d_out;                     // [NA,128]
  float* fout = (float*)d_out + (size_t)NA * 128;  // [NF,128]

  hipMemsetAsync(ws, 0, zero_bytes, stream);

  k_hist_all<<<(TOTW + 255) / 256, 256, 0, stream>>>(edge_index, a2f, frag_index,
                                                     cnt_src, cnt_all);
  k_wt<<<64, 256, 0, stream>>>(W_atom, Wt);
  {
    int nb = (NSEG + 1023) / 1024;  // 235
    k_scan1<<<nb, 256, 0, stream>>>(cnt_all, rp_all, bsum, NSEG);
    k_scan2<<<1, 1024, 0, stream>>>(bsum, nb);
    k_scan3<<<(NSEG + 255) / 256, 256, 0, stream>>>(rp_all, bsum, cnt_src, dinv, NSEG);
  }
  k_fill_all<<<(TOTW + 255) / 256, 256, 0, stream>>>(edge_index, a2f, frag_index,
                                                     rp_all, cur_all, lst);

  k_gemm_y  <<<NA / 64, 256, 0, stream>>>(x_atoms, Wt, b_atom, dinv, y);
  k_gather_x<<<NA / 8, 256, 0, stream>>>(rp_all, cnt_all, lst, y, dinv, xnew);
  k_gather_ff<<<NF / 8, 256, 0, stream>>>(rp_all + NA, cnt_all + NA, lst, xnew, ff);
  k_mlp     <<<NF / 32, 256, 0, stream>>>(rp_all + NA + NF, cnt_all + NA + NF, lst,
                                          ff, W_f1, b_f1, W_f2, b_f2, fout);
}

// Round 8
// 317.621 us; speedup vs baseline: 7.5641x; 1.0572x over previous
//
#include <hip/hip_runtime.h>
#include <hip/hip_bf16.h>
#include <cstddef>

#define NA 200000   // atoms
#define EA 800000   // atom-graph edges
#define NF 20000    // fragments
#define EF 60000    // fragment-graph edges
// D = 128, hidden = 256
#define NSEG (NA + 2 * NF)          // concatenated count array length (240000)
#define TOTW (EA + NA + EF)         // fused hist/fill work items (1060000)
#define NC 8                        // XCD-private counter copies

typedef unsigned short ushort_t;
typedef __attribute__((ext_vector_type(8))) short bf16x8;
typedef __attribute__((ext_vector_type(4))) float f32x4;

__device__ __forceinline__ unsigned short f2bf(float f) {
  unsigned u = __builtin_bit_cast(unsigned, f);
  u += 0x7FFFu + ((u >> 16) & 1u);  // round-to-nearest-even
  return (unsigned short)(u >> 16);
}
__device__ __forceinline__ float bf2f(unsigned short h) {
  unsigned u = ((unsigned)h) << 16;
  return __builtin_bit_cast(float, u);
}

// ================= fused histogram, XCD-privatized ==========================
// copy c = blockIdx.x & 7: with round-robin block->XCD dispatch each copy is
// touched by one XCD only -> atomics stay in the local L2 (no cross-XCD
// line ping-pong). Correctness does not depend on the mapping.
__global__ __launch_bounds__(256) void k_hist_all(
    const int* __restrict__ ei, const int* __restrict__ a2f,
    const int* __restrict__ fi, int* __restrict__ src8,
    int* __restrict__ cnt8) {
  int idx = blockIdx.x * 256 + threadIdx.x;
  const int c = blockIdx.x & (NC - 1);
  if (idx < EA) {
    atomicAdd(&src8[c * NA + ei[idx]], 1);
    atomicAdd(&cnt8[c * NSEG + ei[EA + idx]], 1);
  } else if (idx < EA + NA) {
    atomicAdd(&cnt8[c * NSEG + NA + a2f[idx - EA]], 1);
  } else if (idx < TOTW) {
    atomicAdd(&cnt8[c * NSEG + NA + NF + fi[EF + (idx - EA - NA)]], 1);
  }
}

// ============ reduce 8 copies: totals + per-copy prefix + dinv ==============
__global__ __launch_bounds__(256) void k_reduce8(
    int* __restrict__ cnt8, const int* __restrict__ src8,
    int* __restrict__ cnt_all, float* __restrict__ dinv) {
  int i = blockIdx.x * 256 + threadIdx.x;
  if (i < NSEG) {
    int s = 0;
#pragma unroll
    for (int c = 0; c < NC; ++c) {
      int t = cnt8[c * NSEG + i];
      cnt8[c * NSEG + i] = s;  // exclusive prefix over copies
      s += t;
    }
    cnt_all[i] = s;
  }
  if (i < NA) {
    int d = 0;
#pragma unroll
    for (int c = 0; c < NC; ++c) d += src8[c * NA + i];
    dinv[i] = rsqrtf((float)(1 + d));
  }
}

// ================= exclusive scan over cnt_all ==============================
__global__ __launch_bounds__(256) void k_scan1(const int* __restrict__ cnt,
                                               int* __restrict__ rp,
                                               int* __restrict__ bsum, int n) {
  __shared__ int sh[256];
  const int base = blockIdx.x * 1024;
  const int tid = threadIdx.x;
  int v[4], s = 0;
#pragma unroll
  for (int j = 0; j < 4; ++j) {
    int idx = base + tid * 4 + j;
    v[j] = (idx < n) ? cnt[idx] : 0;
    s += v[j];
  }
  sh[tid] = s;
  __syncthreads();
  for (int off = 1; off < 256; off <<= 1) {
    int t = (tid >= off) ? sh[tid - off] : 0;
    __syncthreads();
    sh[tid] += t;
    __syncthreads();
  }
  int excl = (tid > 0) ? sh[tid - 1] : 0;
#pragma unroll
  for (int j = 0; j < 4; ++j) {
    int idx = base + tid * 4 + j;
    if (idx < n) rp[idx] = excl;
    excl += v[j];
  }
  if (tid == 255) bsum[blockIdx.x] = sh[255];
}
__global__ __launch_bounds__(1024) void k_scan2(int* __restrict__ bsum, int nb) {
  __shared__ int sh[1024];
  const int tid = threadIdx.x;
  sh[tid] = (tid < nb) ? bsum[tid] : 0;
  __syncthreads();
  for (int off = 1; off < 1024; off <<= 1) {
    int t = (tid >= off) ? sh[tid - off] : 0;
    __syncthreads();
    sh[tid] += t;
    __syncthreads();
  }
  if (tid < nb) bsum[tid] = (tid > 0) ? sh[tid - 1] : 0;  // exclusive
}
__global__ __launch_bounds__(256) void k_scan3(int* __restrict__ rp,
                                               const int* __restrict__ bsum,
                                               int n) {
  int i = blockIdx.x * 256 + threadIdx.x;
  if (i < n) rp[i] += bsum[i >> 10];
}

// ================= fused CSR fill, XCD-privatized cursors ===================
// Same idx->block->copy mapping as k_hist_all, so per-(copy,seg) counts agree.
__global__ __launch_bounds__(256) void k_fill_all(
    const int* __restrict__ ei, const int* __restrict__ a2f,
    const int* __restrict__ fi, const int* __restrict__ rp,
    const int* __restrict__ pfx8, int* __restrict__ cur8,
    int* __restrict__ lst) {
  int idx = blockIdx.x * 256 + threadIdx.x;
  const int c = blockIdx.x & (NC - 1);
  if (idx < EA) {
    int t = ei[EA + idx];
    int p = atomicAdd(&cur8[c * NSEG + t], 1);
    lst[rp[t] + pfx8[c * NSEG + t] + p] = ei[idx];           // src atom
  } else if (idx < EA + NA) {
    int i = idx - EA;
    int t = NA + a2f[i];
    int p = atomicAdd(&cur8[c * NSEG + t], 1);
    lst[rp[t] + pfx8[c * NSEG + t] + p] = i;                 // atom id
  } else if (idx < TOTW) {
    int e = idx - EA - NA;
    int t = NA + NF + fi[EF + e];
    int p = atomicAdd(&cur8[c * NSEG + t], 1);
    lst[rp[t] + pfx8[c * NSEG + t] + p] = fi[e];             // fs
  }
}

// ======== Wt[c][k] = bf16(W[k][c]) — tiny precompute ========================
__global__ __launch_bounds__(256) void k_wt(const float* __restrict__ W,
                                            ushort_t* __restrict__ Wt) {
  int idx = blockIdx.x * 256 + threadIdx.x;  // 16384
  if (idx < 128 * 128) {
    int c = idx >> 7, k = idx & 127;
    Wt[idx] = f2bf(W[k * 128 + c]);
  }
}

// ======== y = bf16( (x_atoms @ W_atom + b_atom) * dinv[row] ) — MFMA ========
__global__ __launch_bounds__(256) void k_gemm_y(
    const float* __restrict__ xa, const ushort_t* __restrict__ Wt,
    const float* __restrict__ b, const float* __restrict__ dinv,
    ushort_t* __restrict__ y) {
  __shared__ ushort_t Asl[64 * 128];   // 16 KB, swizzled bf16 A
  __shared__ ushort_t Bsl[128 * 128];  // 32 KB, swizzled bf16 Wt
  const int tid = threadIdx.x;
  const int brow = blockIdx.x * 64;
  {  // stage A: cvt to bf16, swizzled ds_write (8 B units)
    const float4* gA = reinterpret_cast<const float4*>(xa + (size_t)brow * 128);
#pragma unroll
    for (int i = 0; i < 8; ++i) {
      int f = tid + i * 256;
      int row = f >> 5;
      int kq = f & 31;
      float4 v = gA[f];
      ushort4 u;
      u.x = f2bf(v.x); u.y = f2bf(v.y); u.z = f2bf(v.z); u.w = f2bf(v.w);
      int koff = (kq * 4) ^ ((row & 7) << 3);
      *reinterpret_cast<ushort4*>(&Asl[row * 128 + koff]) = u;
    }
    const uint4* gW = reinterpret_cast<const uint4*>(Wt);
#pragma unroll
    for (int i = 0; i < 8; ++i) {
      int u = tid + i * 256;
      int c = u >> 4;
      int k8 = u & 15;
      uint4 v = gW[u];
      int koff = (k8 * 8) ^ ((c & 7) << 3);
      *reinterpret_cast<uint4*>(&Bsl[c * 128 + koff]) = v;
    }
  }
  __syncthreads();
  const int w = tid >> 6;
  const int l = tid & 63;
  const int lr = l & 15;
  const int g = l >> 4;
  const int r0 = w * 16;
  f32x4 acc[8] = {};
  const int arow = r0 + lr;
  const int asw = (arow & 7) << 3;
#pragma unroll
  for (int s = 0; s < 4; ++s) {
    const int kb = s * 32 + g * 4;
    ushort4 alo = *reinterpret_cast<const ushort4*>(&Asl[arow * 128 + (kb ^ asw)]);
    ushort4 ahi = *reinterpret_cast<const ushort4*>(&Asl[arow * 128 + ((kb + 16) ^ asw)]);
    bf16x8 a;
    a[0] = (short)alo.x; a[1] = (short)alo.y; a[2] = (short)alo.z; a[3] = (short)alo.w;
    a[4] = (short)ahi.x; a[5] = (short)ahi.y; a[6] = (short)ahi.z; a[7] = (short)ahi.w;
#pragma unroll
    for (int t = 0; t < 8; ++t) {
      const int bc = t * 16 + lr;
      const int bsw = (bc & 7) << 3;
      ushort4 blo = *reinterpret_cast<const ushort4*>(&Bsl[bc * 128 + (kb ^ bsw)]);
      ushort4 bhi = *reinterpret_cast<const ushort4*>(&Bsl[bc * 128 + ((kb + 16) ^ bsw)]);
      bf16x8 bf;
      bf[0] = (short)blo.x; bf[1] = (short)blo.y; bf[2] = (short)blo.z; bf[3] = (short)blo.w;
      bf[4] = (short)bhi.x; bf[5] = (short)bhi.y; bf[6] = (short)bhi.z; bf[7] = (short)bhi.w;
      acc[t] = __builtin_amdgcn_mfma_f32_16x16x32_bf16(a, bf, acc[t], 0, 0, 0);
    }
  }
  float di[4];
#pragma unroll
  for (int r = 0; r < 4; ++r) di[r] = dinv[brow + r0 + g * 4 + r];
#pragma unroll
  for (int t = 0; t < 8; ++t) {
    const int col = t * 16 + lr;
    const float bb = b[col];
#pragma unroll
    for (int r = 0; r < 4; ++r) {
      const int row = brow + r0 + g * 4 + r;
      y[(size_t)row * 128 + col] = f2bf((acc[t][r] + bb) * di[r]);
    }
  }
}

// ======== x_new[t] = dinv[t] * (y[t] + sum_{s->t} y[s])  (CSR gather) =======
// Batch-4 neighbor loads (ILP); nontemporal xnew store so the 102 MB stream
// doesn't evict y (51 MB) from L3 between re-reads.
__global__ __launch_bounds__(256) void k_gather_x(
    const int* __restrict__ rp, const int* __restrict__ cnt,
    const int* __restrict__ lst, const ushort_t* __restrict__ y,
    const float* __restrict__ dinv, float* __restrict__ xnew) {
  const int row = blockIdx.x * 8 + (threadIdx.x >> 5);
  const int c = (threadIdx.x & 31) << 2;
  const ushort4 vs = *reinterpret_cast<const ushort4*>(y + (size_t)row * 128 + c);
  f32x4 acc = {bf2f(vs.x), bf2f(vs.y), bf2f(vs.z), bf2f(vs.w)};
  const int start = rp[row];
  const int deg = cnt[row];
  int j = 0;
  for (; j + 4 <= deg; j += 4) {
    const int s0 = lst[start + j + 0];
    const int s1 = lst[start + j + 1];
    const int s2 = lst[start + j + 2];
    const int s3 = lst[start + j + 3];
    const ushort4 v0 = *reinterpret_cast<const ushort4*>(y + (size_t)s0 * 128 + c);
    const ushort4 v1 = *reinterpret_cast<const ushort4*>(y + (size_t)s1 * 128 + c);
    const ushort4 v2 = *reinterpret_cast<const ushort4*>(y + (size_t)s2 * 128 + c);
    const ushort4 v3 = *reinterpret_cast<const ushort4*>(y + (size_t)s3 * 128 + c);
    acc.x += bf2f(v0.x) + bf2f(v1.x) + bf2f(v2.x) + bf2f(v3.x);
    acc.y += bf2f(v0.y) + bf2f(v1.y) + bf2f(v2.y) + bf2f(v3.y);
    acc.z += bf2f(v0.z) + bf2f(v1.z) + bf2f(v2.z) + bf2f(v3.z);
    acc.w += bf2f(v0.w) + bf2f(v1.w) + bf2f(v2.w) + bf2f(v3.w);
  }
  for (; j < deg; ++j) {
    const int s = lst[start + j];
    const ushort4 v = *reinterpret_cast<const ushort4*>(y + (size_t)s * 128 + c);
    acc.x += bf2f(v.x); acc.y += bf2f(v.y); acc.z += bf2f(v.z); acc.w += bf2f(v.w);
  }
  const float dt = dinv[row];
  acc.x *= dt; acc.y *= dt; acc.z *= dt; acc.w *= dt;
  __builtin_nontemporal_store(acc, reinterpret_cast<f32x4*>(xnew + (size_t)row * 128 + c));
}

// ======== ff[f] = sum_{atoms i in f} xnew[i]  (CSR gather) ==================
__global__ __launch_bounds__(256) void k_gather_ff(
    const int* __restrict__ rp, const int* __restrict__ cnt,
    const int* __restrict__ lst, const float* __restrict__ xnew,
    float* __restrict__ ff) {
  const int f = blockIdx.x * 8 + (threadIdx.x >> 5);
  const int c = (threadIdx.x & 31) << 2;
  float4 acc = {0.f, 0.f, 0.f, 0.f};
  const int start = rp[f];
  const int deg = cnt[f];
  int j = 0;
  for (; j + 4 <= deg; j += 4) {
    const int s0 = lst[start + j + 0];
    const int s1 = lst[start + j + 1];
    const int s2 = lst[start + j + 2];
    const int s3 = lst[start + j + 3];
    const float4 v0 = *reinterpret_cast<const float4*>(xnew + (size_t)s0 * 128 + c);
    const float4 v1 = *reinterpret_cast<const float4*>(xnew + (size_t)s1 * 128 + c);
    const float4 v2 = *reinterpret_cast<const float4*>(xnew + (size_t)s2 * 128 + c);
    const float4 v3 = *reinterpret_cast<const float4*>(xnew + (size_t)s3 * 128 + c);
    acc.x += v0.x + v1.x + v2.x + v3.x;
    acc.y += v0.y + v1.y + v2.y + v3.y;
    acc.z += v0.z + v1.z + v2.z + v3.z;
    acc.w += v0.w + v1.w + v2.w + v3.w;
  }
  for (; j < deg; ++j) {
    const int s = lst[start + j];
    const float4 v = *reinterpret_cast<const float4*>(xnew + (size_t)s * 128 + c);
    acc.x += v.x; acc.y += v.y; acc.z += v.z; acc.w += v.w;
  }
  *reinterpret_cast<float4*>(ff + (size_t)f * 128 + c) = acc;
}

// ======== fused: fsum gather (frag edges) + 2-layer MLP =====================
__global__ __launch_bounds__(256) void k_mlp(
    const int* __restrict__ rp, const int* __restrict__ cnt,
    const int* __restrict__ lst, const float* __restrict__ ff,
    const float* __restrict__ W1, const float* __restrict__ b1,
    const float* __restrict__ W2, const float* __restrict__ b2,
    float* __restrict__ out) {
  __shared__ float As[32][128];
  __shared__ float hs[32][256];
  const int row0 = blockIdx.x * 32;
  {  // gather: 8 groups x 32 lanes; each group handles 4 rows
    const int g = threadIdx.x >> 5;
    const int c = (threadIdx.x & 31) << 2;
#pragma unroll
    for (int rr = 0; rr < 4; ++rr) {
      const int f = row0 + g * 4 + rr;
      const int start = rp[f];
      const int deg = cnt[f];
      float4 acc = {0.f, 0.f, 0.f, 0.f};
      for (int j = 0; j < deg; ++j) {
        const int s = lst[start + j];
        const float4 v = *reinterpret_cast<const float4*>(ff + (size_t)s * 128 + c);
        acc.x += v.x; acc.y += v.y; acc.z += v.z; acc.w += v.w;
      }
      *reinterpret_cast<float4*>(&As[g * 4 + rr][c]) = acc;
    }
  }
  __syncthreads();
  {  // GEMM1
    const int tc = threadIdx.x & 63;
    const int tr = threadIdx.x >> 6;
    const int c0 = tc * 4;
    float acc[8][4] = {};
    for (int k0 = 0; k0 < 128; k0 += 4) {
      float4 w0 = *reinterpret_cast<const float4*>(&W1[(k0 + 0) * 256 + c0]);
      float4 w1 = *reinterpret_cast<const float4*>(&W1[(k0 + 1) * 256 + c0]);
      float4 w2 = *reinterpret_cast<const float4*>(&W1[(k0 + 2) * 256 + c0]);
      float4 w3 = *reinterpret_cast<const float4*>(&W1[(k0 + 3) * 256 + c0]);
#pragma unroll
      for (int r = 0; r < 8; ++r) {
        float4 a = *reinterpret_cast<const float4*>(&As[tr * 8 + r][k0]);
        acc[r][0] += a.x * w0.x + a.y * w1.x + a.z * w2.x + a.w * w3.x;
        acc[r][1] += a.x * w0.y + a.y * w1.y + a.z * w2.y + a.w * w3.y;
        acc[r][2] += a.x * w0.z + a.y * w1.z + a.z * w2.z + a.w * w3.z;
        acc[r][3] += a.x * w0.w + a.y * w1.w + a.z * w2.w + a.w * w3.w;
      }
    }
    const float4 bc = *reinterpret_cast<const float4*>(&b1[c0]);
#pragma unroll
    for (int r = 0; r < 8; ++r) {
      float4 h;
      h.x = fmaxf(acc[r][0] + bc.x, 0.f);
      h.y = fmaxf(acc[r][1] + bc.y, 0.f);
      h.z = fmaxf(acc[r][2] + bc.z, 0.f);
      h.w = fmaxf(acc[r][3] + bc.w, 0.f);
      *reinterpret_cast<float4*>(&hs[tr * 8 + r][c0]) = h;
    }
  }
  __syncthreads();
  {  // GEMM2
    const int tc = threadIdx.x & 31;
    const int tr = threadIdx.x >> 5;
    const int c0 = tc * 4;
    float acc[4][4] = {};
    for (int k0 = 0; k0 < 256; k0 += 4) {
      float4 w0 = *reinterpret_cast<const float4*>(&W2[(k0 + 0) * 128 + c0]);
      float4 w1 = *reinterpret_cast<const float4*>(&W2[(k0 + 1) * 128 + c0]);
      float4 w2 = *reinterpret_cast<const float4*>(&W2[(k0 + 2) * 128 + c0]);
      float4 w3 = *reinterpret_cast<const float4*>(&W2[(k0 + 3) * 128 + c0]);
#pragma unroll
      for (int r = 0; r < 4; ++r) {
        float4 a = *reinterpret_cast<const float4*>(&hs[tr * 4 + r][k0]);
        acc[r][0] += a.x * w0.x + a.y * w1.x + a.z * w2.x + a.w * w3.x;
        acc[r][1] += a.x * w0.y + a.y * w1.y + a.z * w2.y + a.w * w3.y;
        acc[r][2] += a.x * w0.z + a.y * w1.z + a.z * w2.z + a.w * w3.z;
        acc[r][3] += a.x * w0.w + a.y * w1.w + a.z * w2.w + a.w * w3.w;
      }
    }
    const float4 bc = *reinterpret_cast<const float4*>(&b2[c0]);
#pragma unroll
    for (int r = 0; r < 4; ++r) {
      float4 o;
      o.x = acc[r][0] + bc.x;
      o.y = acc[r][1] + bc.y;
      o.z = acc[r][2] + bc.z;
      o.w = acc[r][3] + bc.w;
      *reinterpret_cast<float4*>(&out[(size_t)(row0 + tr * 4 + r) * 128 + c0]) = o;
    }
  }
}

extern "C" void kernel_launch(void* const* d_in, const int* in_sizes, int n_in,
                              void* d_out, int out_size, void* d_ws, size_t ws_size,
                              hipStream_t stream) {
  // Bond-graph GAT inputs are dead code w.r.t. the returned outputs.
  const float* x_atoms    = (const float*)d_in[0];
  const int*   edge_index = (const int*)d_in[1];
  const int*   frag_index = (const int*)d_in[3];
  const int*   a2f        = (const int*)d_in[5];
  const float* W_atom     = (const float*)d_in[9];
  const float* b_atom     = (const float*)d_in[10];
  const float* W_f1       = (const float*)d_in[16];
  const float* b_f1       = (const float*)d_in[17];
  const float* W_f2       = (const float*)d_in[18];
  const float* b_f2       = (const float*)d_in[19];

  char* ws = (char*)d_ws;
  size_t off = 0;
  auto alloc = [&](size_t bytes) {
    void* p = ws + off;
    off += (bytes + 255) & ~(size_t)255;
    return p;
  };
  // --- zeroed-each-call pool (XCD-private counters/cursors) ---
  int* src8 = (int*)alloc((size_t)NC * NA * 4);     // 6.4 MB
  int* cnt8 = (int*)alloc((size_t)NC * NSEG * 4);   // 7.7 MB (-> per-copy prefix)
  int* cur8 = (int*)alloc((size_t)NC * NSEG * 4);   // 7.7 MB
  const size_t zero_bytes = off;
  // --- rebuilt-each-call ---
  int* cnt_all = (int*)alloc((size_t)NSEG * 4);
  int* rp_all  = (int*)alloc(((size_t)NSEG + 1) * 4);
  int* bsum    = (int*)alloc(1024 * 4);
  int* lst     = (int*)alloc((size_t)TOTW * 4);
  float* dinv  = (float*)alloc((size_t)NA * 4);
  ushort_t* Wt = (ushort_t*)alloc((size_t)128 * 128 * 2);  // bf16 W^T
  ushort_t* y  = (ushort_t*)alloc((size_t)NA * 128 * 2);   // bf16
  float* ff    = (float*)alloc((size_t)NF * 128 * 4);

  float* xnew = (float*)d_out;                     // [NA,128]
  float* fout = (float*)d_out + (size_t)NA * 128;  // [NF,128]

  (void)hipMemsetAsync(ws, 0, zero_bytes, stream);

  k_hist_all<<<(TOTW + 255) / 256, 256, 0, stream>>>(edge_index, a2f, frag_index,
                                                     src8, cnt8);
  k_wt<<<64, 256, 0, stream>>>(W_atom, Wt);
  k_reduce8<<<(NSEG + 255) / 256, 256, 0, stream>>>(cnt8, src8, cnt_all, dinv);
  {
    int nb = (NSEG + 1023) / 1024;  // 235
    k_scan1<<<nb, 256, 0, stream>>>(cnt_all, rp_all, bsum, NSEG);
    k_scan2<<<1, 1024, 0, stream>>>(bsum, nb);
    k_scan3<<<(NSEG + 255) / 256, 256, 0, stream>>>(rp_all, bsum, NSEG);
  }
  k_fill_all<<<(TOTW + 255) / 256, 256, 0, stream>>>(edge_index, a2f, frag_index,
                                                     rp_all, cnt8, cur8, lst);

  k_gemm_y  <<<NA / 64, 256, 0, stream>>>(x_atoms, Wt, b_atom, dinv, y);
  k_gather_x<<<NA / 8, 256, 0, stream>>>(rp_all, cnt_all, lst, y, dinv, xnew);
  k_gather_ff<<<NF / 8, 256, 0, stream>>>(rp_all + NA, cnt_all + NA, lst, xnew, ff);
  k_mlp     <<<NF / 32, 256, 0, stream>>>(rp_all + NA + NF, cnt_all + NA + NF, lst,
                                          ff, W_f1, b_f1, W_f2, b_f2, fout);
}